// Round 7
// baseline (586.892 us; speedup 1.0000x reference)
//
#include <hip/hip_runtime.h>
#include <hip/hip_bf16.h>

#define BB 32
#define SS 512
#define HH 768
#define MAXC 128
#define FEPS 1e-8f

// d_out layout (floats, concatenated tuple in return order)
#define NSCORES (BB*MAXC*MAXC)            // 524288
#define OFF_KVALID (NSCORES)              // 524288
#define OFF_VVALID (OFF_KVALID + BB*MAXC) // 528384
#define OFF_KIDX   (OFF_VVALID + BB*MAXC) // 532480
#define OFF_VIDX   (OFF_KIDX + BB*MAXC)   // 536576

__device__ __forceinline__ unsigned int asc_map(float f) {
    unsigned int u = __float_as_uint(f);
    return (u & 0x80000000u) ? ~u : (u | 0x80000000u);
}

// ---------------- Stage 1: softmax/argmax/conf + stable top-128 ----------------
__global__ void topk_kernel(const float* __restrict__ logits,
                            const int* __restrict__ mask,
                            float* __restrict__ out,
                            int* __restrict__ kidx, int* __restrict__ vidx) {
    int z = blockIdx.x;
    int b = z >> 1;
    int which = z & 1;
    int t = threadIdx.x; // sequence position 0..511
    __shared__ unsigned long long keys[SS];

    const float* l = logits + ((size_t)b * SS + t) * 3;
    float l0 = l[0], l1 = l[1], l2 = l[2];
    int pred = 0; float best = l0;
    if (l1 > best) { best = l1; pred = 1; }
    if (l2 > best) { pred = 2; }
    float m = fmaxf(l0, fmaxf(l1, l2));
    float e0 = expf(l0 - m), e1 = expf(l1 - m), e2 = expf(l2 - m);
    float denom = e0 + e1 + e2;
    float p = (which == 0 ? e1 : e2) / denom;
    int want = which + 1;
    bool ok = (pred == want) && (mask[b * SS + t] == 1);
    float conf = ok ? p : -__builtin_inff();

    unsigned int d = ~asc_map(conf); // descending order map
    keys[t] = ((unsigned long long)d << 32) | (unsigned int)t;
    __syncthreads();

    for (int k = 2; k <= SS; k <<= 1) {
        for (int j = k >> 1; j > 0; j >>= 1) {
            int ixj = t ^ j;
            if (ixj > t) {
                unsigned long long a = keys[t], c = keys[ixj];
                bool up = ((t & k) == 0);
                bool sw = up ? (a > c) : (a < c);
                if (sw) { keys[t] = c; keys[ixj] = a; }
            }
            __syncthreads();
        }
    }

    if (t < MAXC) {
        unsigned long long kk = keys[t];
        int idx = (int)(kk & 0xFFFFFFFFu);
        bool valid = ((unsigned int)(kk >> 32)) != 0xFF800000u; // != map(-inf)
        if (which == 0) {
            kidx[b * MAXC + t] = idx;
            out[OFF_KVALID + b * MAXC + t] = valid ? 1.0f : 0.0f;
            out[OFF_KIDX + b * MAXC + t] = (float)idx;
        } else {
            vidx[b * MAXC + t] = idx;
            out[OFF_VVALID + b * MAXC + t] = valid ? 1.0f : 0.0f;
            out[OFF_VIDX + b * MAXC + t] = (float)idx;
        }
    }
}

// ---------------- Shared GEMM body: 64x64 tile, BK=16, ping-pong LDS ----------------
// 1 barrier per K-step: compute buf[cur] while storing prefetched tile to
// buf[cur^1] (safe: buf[cur^1] was last read before the PREVIOUS barrier).
struct GemmSmem {
    float As[2][16 * 68]; // [k][m], stride 68
    float Bs[2][16 * 68]; // [k][n], stride 68
};

__device__ __forceinline__ void gemm_body(GemmSmem& sm,
                                          const float* __restrict__ Arow, // &A[arow*HH]
                                          const float* __restrict__ Wp,   // W + bkk*HH + n0 + bnq*4
                                          const float* __restrict__ bias,
                                          float* __restrict__ C,
                                          int m0, int n0, int t) {
    const int N = HH, K = HH;
    int tm = t >> 4, tn = t & 15;
    int lrow = t >> 2, lkq = t & 3;
    int bkk = t >> 4, bnq = t & 15;

    float acc[4][4];
    #pragma unroll
    for (int i = 0; i < 4; ++i)
        #pragma unroll
        for (int j = 0; j < 4; ++j) acc[i][j] = 0.0f;

    // prologue: tile 0 -> buf 0
    {
        float4 av = *(const float4*)(Arow + lkq * 4);
        float4 bv = *(const float4*)(Wp);
        sm.As[0][(lkq * 4 + 0) * 68 + lrow] = av.x;
        sm.As[0][(lkq * 4 + 1) * 68 + lrow] = av.y;
        sm.As[0][(lkq * 4 + 2) * 68 + lrow] = av.z;
        sm.As[0][(lkq * 4 + 3) * 68 + lrow] = av.w;
        *(float4*)&sm.Bs[0][bkk * 68 + bnq * 4] = bv;
    }
    __syncthreads();

    int cur = 0;
    for (int k0 = 16; k0 < K; k0 += 16) {
        // prefetch next tile (global) -- latency hides under compute below
        float4 av = *(const float4*)(Arow + k0 + lkq * 4);
        float4 bv = *(const float4*)(Wp + (long)k0 * N);

        #pragma unroll
        for (int kk = 0; kk < 16; ++kk) {
            float4 a4 = *(const float4*)&sm.As[cur][kk * 68 + tm * 4];
            float4 b4 = *(const float4*)&sm.Bs[cur][kk * 68 + tn * 4];
            float a[4] = {a4.x, a4.y, a4.z, a4.w};
            float bb2[4] = {b4.x, b4.y, b4.z, b4.w};
            #pragma unroll
            for (int i = 0; i < 4; ++i)
                #pragma unroll
                for (int j = 0; j < 4; ++j) acc[i][j] += a[i] * bb2[j];
        }

        int nxt = cur ^ 1;
        sm.As[nxt][(lkq * 4 + 0) * 68 + lrow] = av.x;
        sm.As[nxt][(lkq * 4 + 1) * 68 + lrow] = av.y;
        sm.As[nxt][(lkq * 4 + 2) * 68 + lrow] = av.z;
        sm.As[nxt][(lkq * 4 + 3) * 68 + lrow] = av.w;
        *(float4*)&sm.Bs[nxt][bkk * 68 + bnq * 4] = bv;
        __syncthreads();
        cur = nxt;
    }

    // last tile
    #pragma unroll
    for (int kk = 0; kk < 16; ++kk) {
        float4 a4 = *(const float4*)&sm.As[cur][kk * 68 + tm * 4];
        float4 b4 = *(const float4*)&sm.Bs[cur][kk * 68 + tn * 4];
        float a[4] = {a4.x, a4.y, a4.z, a4.w};
        float bb2[4] = {b4.x, b4.y, b4.z, b4.w};
        #pragma unroll
        for (int i = 0; i < 4; ++i)
            #pragma unroll
            for (int j = 0; j < 4; ++j) acc[i][j] += a[i] * bb2[j];
    }

    #pragma unroll
    for (int i = 0; i < 4; ++i) {
        #pragma unroll
        for (int j = 0; j < 4; ++j) {
            int n = n0 + tn * 4 + j;
            float v = acc[i][j];
            if (bias) v += bias[n];
            C[(long)(m0 + tm * 4 + i) * N + n] = v;
        }
    }
}

// Generic (optionally row-gathered) GEMM — used for U = Wk @ Wbil (idx=null)
__global__ void gemm_rowgather(const float* __restrict__ A,
                               const float* __restrict__ W,
                               const float* __restrict__ bias,
                               float* __restrict__ C,
                               const int* __restrict__ idx) {
    __shared__ GemmSmem sm;
    int t = threadIdx.x;
    int m0 = blockIdx.y * 64, n0 = blockIdx.x * 64;
    int gm = m0 + (t >> 2);
    long arow = idx ? ((long)(gm >> 7) * SS + idx[gm]) : gm;
    gemm_body(sm, A + arow * (long)HH,
              W + (long)(t >> 4) * HH + n0 + (t & 15) * 4, bias, C, m0, n0, t);
}

// Dual gathered GEMM: z=0 -> tmp = gather_k(seq)@U + c ; z=1 -> val = gather_v(seq)@Wv + bv
__global__ void gemm_dual(const float* __restrict__ seq,
                          const float* __restrict__ U, const float* __restrict__ cvec,
                          const float* __restrict__ Wv, const float* __restrict__ bv,
                          const int* __restrict__ kidx, const int* __restrict__ vidx,
                          float* __restrict__ tmp, float* __restrict__ valr) {
    __shared__ GemmSmem sm;
    int t = threadIdx.x;
    int m0 = blockIdx.y * 64, n0 = blockIdx.x * 64;
    int z = blockIdx.z;
    const int* idx = z ? vidx : kidx;
    const float* W = z ? Wv : U;
    const float* bias = z ? bv : cvec;
    float* C = z ? valr : tmp;
    int gm = m0 + (t >> 2);
    long arow = (long)(gm >> 7) * SS + idx[gm];
    gemm_body(sm, seq + arow * (long)HH,
              W + (long)(t >> 4) * HH + n0 + (t & 15) * 4, bias, C, m0, n0, t);
}

// c[n] = sum_k bk[k] * Wbil[k][n]
__global__ void bias_mm(const float* __restrict__ bk, const float* __restrict__ Wbil,
                        float* __restrict__ c) {
    int n = blockIdx.x * 128 + threadIdx.x;
    float s = 0.0f;
    for (int k = 0; k < HH; ++k) s += bk[k] * Wbil[(long)k * HH + n];
    c[n] = s;
}

// ---------------- Stage 3b: biaffine = tmp . val_reps^T + bbil ----------------
__global__ void biaffine_kernel(const float* __restrict__ TA,  // [B,128,768]
                                const float* __restrict__ VB,  // [B,128,768]
                                const float* __restrict__ bbil,
                                float* __restrict__ biaf) {    // [B,128,128]
    __shared__ __align__(16) float As[16 * 68];
    __shared__ __align__(16) float Bs[16 * 68];
    int b = blockIdx.z;
    int m0 = blockIdx.y * 64, n0 = blockIdx.x * 64;
    int t = threadIdx.x;
    int tm = t >> 4, tn = t & 15;
    int lrow = t >> 2, lkq = t & 3;
    const float* Ap = TA + ((long)b * MAXC + m0 + lrow) * HH + lkq * 4;
    const float* Bp = VB + ((long)b * MAXC + n0 + lrow) * HH + lkq * 4;

    float acc[4][4];
    #pragma unroll
    for (int i = 0; i < 4; ++i)
        #pragma unroll
        for (int j = 0; j < 4; ++j) acc[i][j] = 0.0f;

    for (int k0 = 0; k0 < HH; k0 += 16) {
        float4 av = *(const float4*)(Ap + k0);
        float4 bv = *(const float4*)(Bp + k0);
        As[(lkq * 4 + 0) * 68 + lrow] = av.x;
        As[(lkq * 4 + 1) * 68 + lrow] = av.y;
        As[(lkq * 4 + 2) * 68 + lrow] = av.z;
        As[(lkq * 4 + 3) * 68 + lrow] = av.w;
        Bs[(lkq * 4 + 0) * 68 + lrow] = bv.x;
        Bs[(lkq * 4 + 1) * 68 + lrow] = bv.y;
        Bs[(lkq * 4 + 2) * 68 + lrow] = bv.z;
        Bs[(lkq * 4 + 3) * 68 + lrow] = bv.w;
        __syncthreads();
        #pragma unroll
        for (int kk = 0; kk < 16; ++kk) {
            float4 a4 = *(const float4*)&As[kk * 68 + tm * 4];
            float4 b4 = *(const float4*)&Bs[kk * 68 + tn * 4];
            float a[4] = {a4.x, a4.y, a4.z, a4.w};
            float bb2[4] = {b4.x, b4.y, b4.z, b4.w};
            #pragma unroll
            for (int i = 0; i < 4; ++i)
                #pragma unroll
                for (int j = 0; j < 4; ++j) acc[i][j] += a[i] * bb2[j];
        }
        __syncthreads();
    }

    float bb = bbil[0];
    #pragma unroll
    for (int i = 0; i < 4; ++i)
        #pragma unroll
        for (int j = 0; j < 4; ++j)
            biaf[((long)b * MAXC + m0 + tm * 4 + i) * MAXC + n0 + tn * 4 + j] =
                acc[i][j] + bb;
}

// ---------------- Stage 4: spatial features + fused MLPs + fusion head ----------------
__global__ void spatial_kernel(const float* __restrict__ bboxes,
                               const int* __restrict__ kidx,
                               const int* __restrict__ vidx,
                               const float* __restrict__ biaf,
                               const float* __restrict__ Ws1, const float* __restrict__ bs1,
                               const float* __restrict__ Ws2, const float* __restrict__ bs2,
                               const float* __restrict__ Wf1, const float* __restrict__ bf1,
                               const float* __restrict__ Wf2, const float* __restrict__ bf2,
                               float* __restrict__ out) {
    __shared__ float sW1[8 * 64], sb1[64], sW2[64 * 32], sb2[32];
    __shared__ float sF1[33 * 16], sf1b[16], sF2[16];
    __shared__ float sbf2;
    __shared__ float kb[16][4], vb[16][4];

    int b = blockIdx.z, kt = blockIdx.y, vt = blockIdx.x;
    int t = threadIdx.y * 16 + threadIdx.x;

    for (int i = t; i < 512; i += 256) sW1[i] = Ws1[i];
    for (int i = t; i < 2048; i += 256) sW2[i] = Ws2[i];
    for (int i = t; i < 528; i += 256) sF1[i] = Wf1[i];
    if (t < 64) sb1[t] = bs1[t];
    if (t >= 64 && t < 96) sb2[t - 64] = bs2[t - 64];
    if (t >= 96 && t < 112) sf1b[t - 96] = bf1[t - 96];
    if (t >= 112 && t < 128) sF2[t - 112] = Wf2[t - 112];
    if (t == 128) sbf2 = bf2[0];
    if (t < 64) {
        int r = t >> 2, c = t & 3;
        kb[r][c] = bboxes[((long)b * SS + kidx[b * MAXC + kt * 16 + r]) * 4 + c];
    } else if (t < 192 && t >= 128) {
        int q = t - 128; int r = q >> 2, c = q & 3;
        vb[r][c] = bboxes[((long)b * SS + vidx[b * MAXC + vt * 16 + r]) * 4 + c];
    }
    __syncthreads();

    int kr = threadIdx.y, vc = threadIdx.x;
    float k1 = kb[kr][0], k2 = kb[kr][1], k3 = kb[kr][2], k4 = kb[kr][3];
    float v1 = vb[vc][0], v2 = vb[vc][1], v3 = vb[vc][2], v4 = vb[vc][3];
    float kcx = (k1 + k3) * 0.5f, kcy = (k2 + k4) * 0.5f;
    float vcx = (v1 + v3) * 0.5f, vcy = (v2 + v4) * 0.5f;
    float dx = vcx - kcx, dy = vcy - kcy;
    float dist = sqrtf(dx * dx + dy * dy + FEPS);
    float angle = atan2f(dy, dx);
    float kh = k4 - k2, kw = k3 - k1, vh = v4 - v2, vw = v3 - v1;
    float h_ov = fmaxf(fminf(k4, v4) - fmaxf(k2, v2), 0.0f);
    float h_align = h_ov / (fminf(kh, vh) + FEPS);
    float v_ov = fmaxf(fminf(k3, v3) - fmaxf(k1, v1), 0.0f);
    float v_align = v_ov / (fminf(kw, vw) + FEPS);
    float area = (vh * vw) / (kh * kw + FEPS);
    float aspect = (vw / (vh + FEPS)) / (kw / (kh + FEPS));
    float sf[8] = {dx, dy, dist, angle, h_align, v_align, area, aspect};

    // Fused MLP: layer1 row i -> immediately accumulated into h2[32]
    float h2[32];
    #pragma unroll
    for (int j = 0; j < 32; ++j) h2[j] = sb2[j];
    #pragma unroll 4
    for (int i = 0; i < 64; ++i) {
        float a = sb1[i];
        #pragma unroll
        for (int q = 0; q < 8; ++q) a += sf[q] * sW1[q * 64 + i];
        a = fmaxf(a, 0.0f);
        #pragma unroll
        for (int j = 0; j < 32; ++j) h2[j] += a * sW2[i * 32 + j];
    }

    int k = kt * 16 + kr, v = vt * 16 + vc;
    float bia = biaf[((long)b * MAXC + k) * MAXC + v];
    float sc = sbf2;
    #pragma unroll
    for (int j = 0; j < 16; ++j) {
        float f = sf1b[j] + bia * sF1[0 * 16 + j];
        #pragma unroll
        for (int i = 0; i < 32; ++i) f += h2[i] * sF1[(i + 1) * 16 + j];
        f = fmaxf(f, 0.0f);
        sc += f * sF2[j];
    }
    out[((long)b * MAXC + k) * MAXC + v] = sc;
}

extern "C" void kernel_launch(void* const* d_in, const int* in_sizes, int n_in,
                              void* d_out, int out_size, void* d_ws, size_t ws_size,
                              hipStream_t stream) {
    const float* seq    = (const float*)d_in[0];
    const float* logits = (const float*)d_in[1];
    const float* bboxes = (const float*)d_in[2];
    const int*   mask   = (const int*)d_in[3];
    const float* Wk  = (const float*)d_in[4];
    const float* bk  = (const float*)d_in[5];
    const float* Wv  = (const float*)d_in[6];
    const float* bv  = (const float*)d_in[7];
    const float* Wbil = (const float*)d_in[8];
    const float* bbil = (const float*)d_in[9];
    const float* Ws1 = (const float*)d_in[10];
    const float* bs1 = (const float*)d_in[11];
    const float* Ws2 = (const float*)d_in[12];
    const float* bs2 = (const float*)d_in[13];
    const float* Wf1 = (const float*)d_in[14];
    const float* bf1 = (const float*)d_in[15];
    const float* Wf2 = (const float*)d_in[16];
    const float* bf2 = (const float*)d_in[17];
    float* out = (float*)d_out;

    // workspace layout
    int* kidx = (int*)d_ws;
    int* vidx = kidx + BB * MAXC;
    float* U        = (float*)(vidx + BB * MAXC);            // [768,768]
    float* cvec     = U + (size_t)HH * HH;                   // [768]
    float* tmp      = cvec + HH;                             // [4096,768]
    float* val_reps = tmp + (size_t)BB * MAXC * HH;          // [4096,768]
    float* biaf     = val_reps + (size_t)BB * MAXC * HH;     // [32,128,128]

    topk_kernel<<<2 * BB, SS, 0, stream>>>(logits, mask, out, kidx, vidx);
    gemm_rowgather<<<dim3(12, 12), 256, 0, stream>>>(Wk, Wbil, nullptr, U, nullptr);
    bias_mm<<<6, 128, 0, stream>>>(bk, Wbil, cvec);
    gemm_dual<<<dim3(12, 64, 2), 256, 0, stream>>>(seq, U, cvec, Wv, bv,
                                                   kidx, vidx, tmp, val_reps);
    biaffine_kernel<<<dim3(2, 2, BB), 256, 0, stream>>>(tmp, val_reps, bbil, biaf);
    spatial_kernel<<<dim3(8, 8, BB), dim3(16, 16), 0, stream>>>(
        bboxes, kidx, vidx, biaf, Ws1, bs1, Ws2, bs2, Wf1, bf1, Wf2, bf2, out);
}

// Round 8
// 423.545 us; speedup vs baseline: 1.3857x; 1.3857x over previous
//
#include <hip/hip_runtime.h>
#include <hip/hip_bf16.h>

#define BB 32
#define SS 512
#define HH 768
#define MAXC 128
#define FEPS 1e-8f

// d_out layout (floats, concatenated tuple in return order)
#define NSCORES (BB*MAXC*MAXC)            // 524288
#define OFF_KVALID (NSCORES)              // 524288
#define OFF_VVALID (OFF_KVALID + BB*MAXC) // 528384
#define OFF_KIDX   (OFF_VVALID + BB*MAXC) // 532480
#define OFF_VIDX   (OFF_KIDX + BB*MAXC)   // 536576

__device__ __forceinline__ unsigned int asc_map(float f) {
    unsigned int u = __float_as_uint(f);
    return (u & 0x80000000u) ? ~u : (u | 0x80000000u);
}

// ---------------- Stage 1: softmax/argmax/conf + stable top-128 ----------------
__global__ void topk_kernel(const float* __restrict__ logits,
                            const int* __restrict__ mask,
                            float* __restrict__ out,
                            int* __restrict__ kidx, int* __restrict__ vidx) {
    int z = blockIdx.x;
    int b = z >> 1;
    int which = z & 1;
    int t = threadIdx.x; // sequence position 0..511
    __shared__ unsigned long long keys[SS];

    const float* l = logits + ((size_t)b * SS + t) * 3;
    float l0 = l[0], l1 = l[1], l2 = l[2];
    int pred = 0; float best = l0;
    if (l1 > best) { best = l1; pred = 1; }
    if (l2 > best) { pred = 2; }
    float m = fmaxf(l0, fmaxf(l1, l2));
    float e0 = expf(l0 - m), e1 = expf(l1 - m), e2 = expf(l2 - m);
    float denom = e0 + e1 + e2;
    float p = (which == 0 ? e1 : e2) / denom;
    int want = which + 1;
    bool ok = (pred == want) && (mask[b * SS + t] == 1);
    float conf = ok ? p : -__builtin_inff();

    unsigned int d = ~asc_map(conf); // descending order map
    keys[t] = ((unsigned long long)d << 32) | (unsigned int)t;
    __syncthreads();

    for (int k = 2; k <= SS; k <<= 1) {
        for (int j = k >> 1; j > 0; j >>= 1) {
            int ixj = t ^ j;
            if (ixj > t) {
                unsigned long long a = keys[t], c = keys[ixj];
                bool up = ((t & k) == 0);
                bool sw = up ? (a > c) : (a < c);
                if (sw) { keys[t] = c; keys[ixj] = a; }
            }
            __syncthreads();
        }
    }

    if (t < MAXC) {
        unsigned long long kk = keys[t];
        int idx = (int)(kk & 0xFFFFFFFFu);
        bool valid = ((unsigned int)(kk >> 32)) != 0xFF800000u; // != map(-inf)
        if (which == 0) {
            kidx[b * MAXC + t] = idx;
            out[OFF_KVALID + b * MAXC + t] = valid ? 1.0f : 0.0f;
            out[OFF_KIDX + b * MAXC + t] = (float)idx;
        } else {
            vidx[b * MAXC + t] = idx;
            out[OFF_VVALID + b * MAXC + t] = valid ? 1.0f : 0.0f;
            out[OFF_VIDX + b * MAXC + t] = (float)idx;
        }
    }
}

// ---------------- Shared GEMM body: 64x64 tile, BK=16, single-buffer 2-barrier ----------------
// (R5-proven structure: 85 us/GEMM, VGPR=36, minimal LDS conflicts. The 1-barrier
// ping-pong variant spilled at VGPR=64 and regressed 68% -- do not reintroduce.)
__device__ __forceinline__ void gemm_body(float* __restrict__ As, float* __restrict__ Bs,
                                          const float* __restrict__ Arow, // &A[arow*HH]
                                          const float* __restrict__ Wp,   // W + bkk*HH + n0 + bnq*4
                                          const float* __restrict__ bias,
                                          float* __restrict__ C,
                                          int m0, int n0, int t) {
    const int N = HH, K = HH;
    int tm = t >> 4, tn = t & 15;
    int lrow = t >> 2, lkq = t & 3;
    int bkk = t >> 4, bnq = t & 15;

    float acc[4][4];
    #pragma unroll
    for (int i = 0; i < 4; ++i)
        #pragma unroll
        for (int j = 0; j < 4; ++j) acc[i][j] = 0.0f;

    for (int k0 = 0; k0 < K; k0 += 16) {
        float4 av = *(const float4*)(Arow + k0 + lkq * 4);
        As[(lkq * 4 + 0) * 68 + lrow] = av.x;
        As[(lkq * 4 + 1) * 68 + lrow] = av.y;
        As[(lkq * 4 + 2) * 68 + lrow] = av.z;
        As[(lkq * 4 + 3) * 68 + lrow] = av.w;
        float4 bv = *(const float4*)(Wp + (long)k0 * N);
        *(float4*)&Bs[bkk * 68 + bnq * 4] = bv;
        __syncthreads();
        #pragma unroll
        for (int kk = 0; kk < 16; ++kk) {
            float4 a4 = *(const float4*)&As[kk * 68 + tm * 4];
            float4 b4 = *(const float4*)&Bs[kk * 68 + tn * 4];
            float a[4] = {a4.x, a4.y, a4.z, a4.w};
            float bb2[4] = {b4.x, b4.y, b4.z, b4.w};
            #pragma unroll
            for (int i = 0; i < 4; ++i)
                #pragma unroll
                for (int j = 0; j < 4; ++j) acc[i][j] += a[i] * bb2[j];
        }
        __syncthreads();
    }

    #pragma unroll
    for (int i = 0; i < 4; ++i) {
        #pragma unroll
        for (int j = 0; j < 4; ++j) {
            int n = n0 + tn * 4 + j;
            float v = acc[i][j];
            if (bias) v += bias[n];
            C[(long)(m0 + tm * 4 + i) * N + n] = v;
        }
    }
}

// Generic (optionally row-gathered) GEMM — used for U = Wk @ Wbil (idx=null)
__global__ void gemm_rowgather(const float* __restrict__ A,
                               const float* __restrict__ W,
                               const float* __restrict__ bias,
                               float* __restrict__ C,
                               const int* __restrict__ idx) {
    __shared__ __align__(16) float As[16 * 68];
    __shared__ __align__(16) float Bs[16 * 68];
    int t = threadIdx.x;
    int m0 = blockIdx.y * 64, n0 = blockIdx.x * 64;
    int gm = m0 + (t >> 2);
    long arow = idx ? ((long)(gm >> 7) * SS + idx[gm]) : gm;
    gemm_body(As, Bs, A + arow * (long)HH,
              W + (long)(t >> 4) * HH + n0 + (t & 15) * 4, bias, C, m0, n0, t);
}

// Dual gathered GEMM: z=0 -> tmp = gather_k(seq)@U + c ; z=1 -> val = gather_v(seq)@Wv + bv
__global__ void gemm_dual(const float* __restrict__ seq,
                          const float* __restrict__ U, const float* __restrict__ cvec,
                          const float* __restrict__ Wv, const float* __restrict__ bv,
                          const int* __restrict__ kidx, const int* __restrict__ vidx,
                          float* __restrict__ tmp, float* __restrict__ valr) {
    __shared__ __align__(16) float As[16 * 68];
    __shared__ __align__(16) float Bs[16 * 68];
    int t = threadIdx.x;
    int m0 = blockIdx.y * 64, n0 = blockIdx.x * 64;
    int z = blockIdx.z;
    const int* idx = z ? vidx : kidx;
    const float* W = z ? Wv : U;
    const float* bias = z ? bv : cvec;
    float* C = z ? valr : tmp;
    int gm = m0 + (t >> 2);
    long arow = (long)(gm >> 7) * SS + idx[gm];
    gemm_body(As, Bs, seq + arow * (long)HH,
              W + (long)(t >> 4) * HH + n0 + (t & 15) * 4, bias, C, m0, n0, t);
}

// c[n] = sum_k bk[k] * Wbil[k][n]  -- 768 threads, 4-way ILP accumulators
__global__ void bias_mm(const float* __restrict__ bk, const float* __restrict__ Wbil,
                        float* __restrict__ c) {
    int n = blockIdx.x * 256 + threadIdx.x;
    if (n >= HH) return;
    float s0 = 0.0f, s1 = 0.0f, s2 = 0.0f, s3 = 0.0f;
    #pragma unroll 4
    for (int k = 0; k < HH; k += 4) {
        s0 += bk[k + 0] * Wbil[(long)(k + 0) * HH + n];
        s1 += bk[k + 1] * Wbil[(long)(k + 1) * HH + n];
        s2 += bk[k + 2] * Wbil[(long)(k + 2) * HH + n];
        s3 += bk[k + 3] * Wbil[(long)(k + 3) * HH + n];
    }
    c[n] = (s0 + s1) + (s2 + s3);
}

// ---------------- Stage 3b: biaffine = tmp . val_reps^T + bbil ----------------
__global__ void biaffine_kernel(const float* __restrict__ TA,  // [B,128,768]
                                const float* __restrict__ VB,  // [B,128,768]
                                const float* __restrict__ bbil,
                                float* __restrict__ biaf) {    // [B,128,128]
    __shared__ __align__(16) float As[16 * 68];
    __shared__ __align__(16) float Bs[16 * 68];
    int b = blockIdx.z;
    int m0 = blockIdx.y * 64, n0 = blockIdx.x * 64;
    int t = threadIdx.x;
    int tm = t >> 4, tn = t & 15;
    int lrow = t >> 2, lkq = t & 3;
    const float* Ap = TA + ((long)b * MAXC + m0 + lrow) * HH + lkq * 4;
    const float* Bp = VB + ((long)b * MAXC + n0 + lrow) * HH + lkq * 4;

    float acc[4][4];
    #pragma unroll
    for (int i = 0; i < 4; ++i)
        #pragma unroll
        for (int j = 0; j < 4; ++j) acc[i][j] = 0.0f;

    for (int k0 = 0; k0 < HH; k0 += 16) {
        float4 av = *(const float4*)(Ap + k0);
        float4 bv = *(const float4*)(Bp + k0);
        As[(lkq * 4 + 0) * 68 + lrow] = av.x;
        As[(lkq * 4 + 1) * 68 + lrow] = av.y;
        As[(lkq * 4 + 2) * 68 + lrow] = av.z;
        As[(lkq * 4 + 3) * 68 + lrow] = av.w;
        Bs[(lkq * 4 + 0) * 68 + lrow] = bv.x;
        Bs[(lkq * 4 + 1) * 68 + lrow] = bv.y;
        Bs[(lkq * 4 + 2) * 68 + lrow] = bv.z;
        Bs[(lkq * 4 + 3) * 68 + lrow] = bv.w;
        __syncthreads();
        #pragma unroll
        for (int kk = 0; kk < 16; ++kk) {
            float4 a4 = *(const float4*)&As[kk * 68 + tm * 4];
            float4 b4 = *(const float4*)&Bs[kk * 68 + tn * 4];
            float a[4] = {a4.x, a4.y, a4.z, a4.w};
            float bb2[4] = {b4.x, b4.y, b4.z, b4.w};
            #pragma unroll
            for (int i = 0; i < 4; ++i)
                #pragma unroll
                for (int j = 0; j < 4; ++j) acc[i][j] += a[i] * bb2[j];
        }
        __syncthreads();
    }

    float bb = bbil[0];
    #pragma unroll
    for (int i = 0; i < 4; ++i)
        #pragma unroll
        for (int j = 0; j < 4; ++j)
            biaf[((long)b * MAXC + m0 + tm * 4 + i) * MAXC + n0 + tn * 4 + j] =
                acc[i][j] + bb;
}

// ---------------- Stage 4: spatial features + fused MLPs + fusion head ----------------
__global__ void spatial_kernel(const float* __restrict__ bboxes,
                               const int* __restrict__ kidx,
                               const int* __restrict__ vidx,
                               const float* __restrict__ biaf,
                               const float* __restrict__ Ws1, const float* __restrict__ bs1,
                               const float* __restrict__ Ws2, const float* __restrict__ bs2,
                               const float* __restrict__ Wf1, const float* __restrict__ bf1,
                               const float* __restrict__ Wf2, const float* __restrict__ bf2,
                               float* __restrict__ out) {
    __shared__ float sW1[8 * 64], sb1[64], sW2[64 * 32], sb2[32];
    __shared__ float sF1[33 * 16], sf1b[16], sF2[16];
    __shared__ float sbf2;
    __shared__ float kb[16][4], vb[16][4];

    int b = blockIdx.z, kt = blockIdx.y, vt = blockIdx.x;
    int t = threadIdx.y * 16 + threadIdx.x;

    for (int i = t; i < 512; i += 256) sW1[i] = Ws1[i];
    for (int i = t; i < 2048; i += 256) sW2[i] = Ws2[i];
    for (int i = t; i < 528; i += 256) sF1[i] = Wf1[i];
    if (t < 64) sb1[t] = bs1[t];
    if (t >= 64 && t < 96) sb2[t - 64] = bs2[t - 64];
    if (t >= 96 && t < 112) sf1b[t - 96] = bf1[t - 96];
    if (t >= 112 && t < 128) sF2[t - 112] = Wf2[t - 112];
    if (t == 128) sbf2 = bf2[0];
    if (t < 64) {
        int r = t >> 2, c = t & 3;
        kb[r][c] = bboxes[((long)b * SS + kidx[b * MAXC + kt * 16 + r]) * 4 + c];
    } else if (t < 192 && t >= 128) {
        int q = t - 128; int r = q >> 2, c = q & 3;
        vb[r][c] = bboxes[((long)b * SS + vidx[b * MAXC + vt * 16 + r]) * 4 + c];
    }
    __syncthreads();

    int kr = threadIdx.y, vc = threadIdx.x;
    float k1 = kb[kr][0], k2 = kb[kr][1], k3 = kb[kr][2], k4 = kb[kr][3];
    float v1 = vb[vc][0], v2 = vb[vc][1], v3 = vb[vc][2], v4 = vb[vc][3];
    float kcx = (k1 + k3) * 0.5f, kcy = (k2 + k4) * 0.5f;
    float vcx = (v1 + v3) * 0.5f, vcy = (v2 + v4) * 0.5f;
    float dx = vcx - kcx, dy = vcy - kcy;
    float dist = sqrtf(dx * dx + dy * dy + FEPS);
    float angle = atan2f(dy, dx);
    float kh = k4 - k2, kw = k3 - k1, vh = v4 - v2, vw = v3 - v1;
    float h_ov = fmaxf(fminf(k4, v4) - fmaxf(k2, v2), 0.0f);
    float h_align = h_ov / (fminf(kh, vh) + FEPS);
    float v_ov = fmaxf(fminf(k3, v3) - fmaxf(k1, v1), 0.0f);
    float v_align = v_ov / (fminf(kw, vw) + FEPS);
    float area = (vh * vw) / (kh * kw + FEPS);
    float aspect = (vw / (vh + FEPS)) / (kw / (kh + FEPS));
    float sf[8] = {dx, dy, dist, angle, h_align, v_align, area, aspect};

    // Fused MLP: layer1 row i -> immediately accumulated into h2[32]
    float h2[32];
    #pragma unroll
    for (int j = 0; j < 32; ++j) h2[j] = sb2[j];
    #pragma unroll 4
    for (int i = 0; i < 64; ++i) {
        float a = sb1[i];
        #pragma unroll
        for (int q = 0; q < 8; ++q) a += sf[q] * sW1[q * 64 + i];
        a = fmaxf(a, 0.0f);
        #pragma unroll
        for (int j = 0; j < 32; ++j) h2[j] += a * sW2[i * 32 + j];
    }

    int k = kt * 16 + kr, v = vt * 16 + vc;
    float bia = biaf[((long)b * MAXC + k) * MAXC + v];
    float sc = sbf2;
    #pragma unroll
    for (int j = 0; j < 16; ++j) {
        float f = sf1b[j] + bia * sF1[0 * 16 + j];
        #pragma unroll
        for (int i = 0; i < 32; ++i) f += h2[i] * sF1[(i + 1) * 16 + j];
        f = fmaxf(f, 0.0f);
        sc += f * sF2[j];
    }
    out[((long)b * MAXC + k) * MAXC + v] = sc;
}

extern "C" void kernel_launch(void* const* d_in, const int* in_sizes, int n_in,
                              void* d_out, int out_size, void* d_ws, size_t ws_size,
                              hipStream_t stream) {
    const float* seq    = (const float*)d_in[0];
    const float* logits = (const float*)d_in[1];
    const float* bboxes = (const float*)d_in[2];
    const int*   mask   = (const int*)d_in[3];
    const float* Wk  = (const float*)d_in[4];
    const float* bk  = (const float*)d_in[5];
    const float* Wv  = (const float*)d_in[6];
    const float* bv  = (const float*)d_in[7];
    const float* Wbil = (const float*)d_in[8];
    const float* bbil = (const float*)d_in[9];
    const float* Ws1 = (const float*)d_in[10];
    const float* bs1 = (const float*)d_in[11];
    const float* Ws2 = (const float*)d_in[12];
    const float* bs2 = (const float*)d_in[13];
    const float* Wf1 = (const float*)d_in[14];
    const float* bf1 = (const float*)d_in[15];
    const float* Wf2 = (const float*)d_in[16];
    const float* bf2 = (const float*)d_in[17];
    float* out = (float*)d_out;

    // workspace layout
    int* kidx = (int*)d_ws;
    int* vidx = kidx + BB * MAXC;
    float* U        = (float*)(vidx + BB * MAXC);            // [768,768]
    float* cvec     = U + (size_t)HH * HH;                   // [768]
    float* tmp      = cvec + HH;                             // [4096,768]
    float* val_reps = tmp + (size_t)BB * MAXC * HH;          // [4096,768]
    float* biaf     = val_reps + (size_t)BB * MAXC * HH;     // [32,128,128]

    topk_kernel<<<2 * BB, SS, 0, stream>>>(logits, mask, out, kidx, vidx);
    gemm_rowgather<<<dim3(12, 12), 256, 0, stream>>>(Wk, Wbil, nullptr, U, nullptr);
    bias_mm<<<3, 256, 0, stream>>>(bk, Wbil, cvec);
    gemm_dual<<<dim3(12, 64, 2), 256, 0, stream>>>(seq, U, cvec, Wv, bv,
                                                   kidx, vidx, tmp, val_reps);
    biaffine_kernel<<<dim3(2, 2, BB), 256, 0, stream>>>(tmp, val_reps, bbil, biaf);
    spatial_kernel<<<dim3(8, 8, BB), dim3(16, 16), 0, stream>>>(
        bboxes, kidx, vidx, biaf, Ws1, bs1, Ws2, bs2, Wf1, bf1, Wf2, bf2, out);
}

// Round 10
// 347.006 us; speedup vs baseline: 1.6913x; 1.2206x over previous
//
#include <hip/hip_runtime.h>
#include <hip/hip_bf16.h>

#define BB 32
#define SS 512
#define HH 768
#define MAXC 128
#define FEPS 1e-8f

// d_out layout (floats, concatenated tuple in return order)
#define NSCORES (BB*MAXC*MAXC)            // 524288
#define OFF_KVALID (NSCORES)              // 524288
#define OFF_VVALID (OFF_KVALID + BB*MAXC) // 528384
#define OFF_KIDX   (OFF_VVALID + BB*MAXC) // 532480
#define OFF_VIDX   (OFF_KIDX + BB*MAXC)   // 536576

typedef __attribute__((ext_vector_type(8))) short bhalf8;  // 8 bf16 = 4 VGPR
typedef __attribute__((ext_vector_type(4))) float f32x4;   // MFMA acc

__device__ __forceinline__ unsigned int asc_map(float f) {
    unsigned int u = __float_as_uint(f);
    return (u & 0x80000000u) ? ~u : (u | 0x80000000u);
}

// bf16 split helpers (RNE, header-free)
__device__ __forceinline__ unsigned short f2bf_rne(float x) {
    unsigned u = __float_as_uint(x);
    unsigned r = u + 0x7FFFu + ((u >> 16) & 1u);
    return (unsigned short)(r >> 16);
}
__device__ __forceinline__ float bf2f(unsigned short h) {
    return __uint_as_float(((unsigned)h) << 16);
}
__device__ __forceinline__ void bsplit(float x, unsigned short& h, unsigned short& l) {
    h = f2bf_rne(x);
    l = f2bf_rne(x - bf2f(h));
}
__device__ __forceinline__ void bsplit4(float4 v, ushort4& h, ushort4& l) {
    bsplit(v.x, h.x, l.x); bsplit(v.y, h.y, l.y);
    bsplit(v.z, h.z, l.z); bsplit(v.w, h.w, l.w);
}

// ---------------- Stage 1: softmax/argmax/conf + stable top-128 ----------------
__global__ void topk_kernel(const float* __restrict__ logits,
                            const int* __restrict__ mask,
                            float* __restrict__ out,
                            int* __restrict__ kidx, int* __restrict__ vidx) {
    int z = blockIdx.x;
    int b = z >> 1;
    int which = z & 1;
    int t = threadIdx.x; // sequence position 0..511
    __shared__ unsigned long long keys[SS];

    const float* l = logits + ((size_t)b * SS + t) * 3;
    float l0 = l[0], l1 = l[1], l2 = l[2];
    int pred = 0; float best = l0;
    if (l1 > best) { best = l1; pred = 1; }
    if (l2 > best) { pred = 2; }
    float m = fmaxf(l0, fmaxf(l1, l2));
    float e0 = expf(l0 - m), e1 = expf(l1 - m), e2 = expf(l2 - m);
    float denom = e0 + e1 + e2;
    float p = (which == 0 ? e1 : e2) / denom;
    int want = which + 1;
    bool ok = (pred == want) && (mask[b * SS + t] == 1);
    float conf = ok ? p : -__builtin_inff();

    unsigned int d = ~asc_map(conf); // descending order map
    keys[t] = ((unsigned long long)d << 32) | (unsigned int)t;
    __syncthreads();

    for (int k = 2; k <= SS; k <<= 1) {
        for (int j = k >> 1; j > 0; j >>= 1) {
            int ixj = t ^ j;
            if (ixj > t) {
                unsigned long long a = keys[t], c = keys[ixj];
                bool up = ((t & k) == 0);
                bool sw = up ? (a > c) : (a < c);
                if (sw) { keys[t] = c; keys[ixj] = a; }
            }
            __syncthreads();
        }
    }

    if (t < MAXC) {
        unsigned long long kk = keys[t];
        int idx = (int)(kk & 0xFFFFFFFFu);
        bool valid = ((unsigned int)(kk >> 32)) != 0xFF800000u; // != map(-inf)
        if (which == 0) {
            kidx[b * MAXC + t] = idx;
            out[OFF_KVALID + b * MAXC + t] = valid ? 1.0f : 0.0f;
            out[OFF_KIDX + b * MAXC + t] = (float)idx;
        } else {
            vidx[b * MAXC + t] = idx;
            out[OFF_VVALID + b * MAXC + t] = valid ? 1.0f : 0.0f;
            out[OFF_VIDX + b * MAXC + t] = (float)idx;
        }
    }
}

// ---------------- fp32 GEMM body (proven R5 structure) — used for U = Wk@Wbil ----------------
__device__ __forceinline__ void gemm_body(float* __restrict__ As, float* __restrict__ Bs,
                                          const float* __restrict__ Arow,
                                          const float* __restrict__ Wp,
                                          const float* __restrict__ bias,
                                          float* __restrict__ C,
                                          int m0, int n0, int t) {
    const int N = HH, K = HH;
    int tm = t >> 4, tn = t & 15;
    int lrow = t >> 2, lkq = t & 3;
    int bkk = t >> 4, bnq = t & 15;

    float acc[4][4];
    #pragma unroll
    for (int i = 0; i < 4; ++i)
        #pragma unroll
        for (int j = 0; j < 4; ++j) acc[i][j] = 0.0f;

    for (int k0 = 0; k0 < K; k0 += 16) {
        float4 av = *(const float4*)(Arow + k0 + lkq * 4);
        As[(lkq * 4 + 0) * 68 + lrow] = av.x;
        As[(lkq * 4 + 1) * 68 + lrow] = av.y;
        As[(lkq * 4 + 2) * 68 + lrow] = av.z;
        As[(lkq * 4 + 3) * 68 + lrow] = av.w;
        float4 bv = *(const float4*)(Wp + (long)k0 * N);
        *(float4*)&Bs[bkk * 68 + bnq * 4] = bv;
        __syncthreads();
        #pragma unroll
        for (int kk = 0; kk < 16; ++kk) {
            float4 a4 = *(const float4*)&As[kk * 68 + tm * 4];
            float4 b4 = *(const float4*)&Bs[kk * 68 + tn * 4];
            float a[4] = {a4.x, a4.y, a4.z, a4.w};
            float bb2[4] = {b4.x, b4.y, b4.z, b4.w};
            #pragma unroll
            for (int i = 0; i < 4; ++i)
                #pragma unroll
                for (int j = 0; j < 4; ++j) acc[i][j] += a[i] * bb2[j];
        }
        __syncthreads();
    }

    #pragma unroll
    for (int i = 0; i < 4; ++i) {
        #pragma unroll
        for (int j = 0; j < 4; ++j) {
            int n = n0 + tn * 4 + j;
            float v = acc[i][j];
            if (bias) v += bias[n];
            C[(long)(m0 + tm * 4 + i) * N + n] = v;
        }
    }
}

__global__ void gemm_rowgather(const float* __restrict__ A,
                               const float* __restrict__ W,
                               const float* __restrict__ bias,
                               float* __restrict__ C,
                               const int* __restrict__ idx) {
    __shared__ __align__(16) float As[16 * 68];
    __shared__ __align__(16) float Bs[16 * 68];
    int t = threadIdx.x;
    int m0 = blockIdx.y * 64, n0 = blockIdx.x * 64;
    int gm = m0 + (t >> 2);
    long arow = idx ? ((long)(gm >> 7) * SS + idx[gm]) : gm;
    gemm_body(As, Bs, A + arow * (long)HH,
              W + (long)(t >> 4) * HH + n0 + (t & 15) * 4, bias, C, m0, n0, t);
}

// c[n] = sum_k bk[k] * Wbil[k][n]
__global__ void bias_mm(const float* __restrict__ bk, const float* __restrict__ Wbil,
                        float* __restrict__ c) {
    int n = blockIdx.x * 256 + threadIdx.x;
    if (n >= HH) return;
    float s0 = 0.0f, s1 = 0.0f, s2 = 0.0f, s3 = 0.0f;
    #pragma unroll 4
    for (int k = 0; k < HH; k += 4) {
        s0 += bk[k + 0] * Wbil[(long)(k + 0) * HH + n];
        s1 += bk[k + 1] * Wbil[(long)(k + 1) * HH + n];
        s2 += bk[k + 2] * Wbil[(long)(k + 2) * HH + n];
        s3 += bk[k + 3] * Wbil[(long)(k + 3) * HH + n];
    }
    c[n] = (s0 + s1) + (s2 + s3);
}

// ---------------- 768x768 transpose (z=0: Wv->WvT, z=1: U->UT) ----------------
__global__ void transpose768(const float* __restrict__ Wv, float* __restrict__ WvT,
                             const float* __restrict__ U, float* __restrict__ UT) {
    __shared__ float tile[32][33];
    const float* in  = blockIdx.z ? U  : Wv;
    float*       outp = blockIdx.z ? UT : WvT;
    int bx = blockIdx.x * 32, by = blockIdx.y * 32;
    int tx = threadIdx.x, ty = threadIdx.y; // (32,8)
    #pragma unroll
    for (int i = ty; i < 32; i += 8)
        tile[i][tx] = in[(long)(by + i) * HH + bx + tx];
    __syncthreads();
    #pragma unroll
    for (int i = ty; i < 32; i += 8)
        outp[(long)(bx + i) * HH + by + tx] = tile[tx][i];
}

// ---------------- split-bf16 MFMA dual GEMM ----------------
// z=0: tmp = gather_k(seq) @ U + cvec   (B operand staged from UT [n][k])
// z=1: val = gather_v(seq) @ Wv + bv    (B operand staged from WvT [n][k])
// 64x64 tile, BK=32, 4 waves (each 32x32 via 2x2 16x16 frags), single-buffer 2-barrier.
// A*B ~= Ah*Bh + Ah*Bl + Al*Bh  (bf16 hi/lo split, ~fp32 accuracy)
#define LSTR 40  // LDS row stride in shorts (80 B, 16B-aligned, conflict-light)

__global__ void gemm_dual_mfma(const float* __restrict__ seq,
                               const float* __restrict__ UT, const float* __restrict__ cvec,
                               const float* __restrict__ WvT, const float* __restrict__ bv,
                               const int* __restrict__ kidx, const int* __restrict__ vidx,
                               float* __restrict__ tmp, float* __restrict__ valr) {
    __shared__ unsigned short Ah[64 * LSTR], Al[64 * LSTR];
    __shared__ unsigned short Bh[64 * LSTR], Bl[64 * LSTR];
    int t = threadIdx.x;
    int m0 = blockIdx.y * 64, n0 = blockIdx.x * 64;
    int z = blockIdx.z;
    const int* idx = z ? vidx : kidx;
    const float* WT = z ? WvT : UT;
    const float* bias = z ? bv : cvec;
    float* C = z ? valr : tmp;

    // staging assignment: row r (0..63), float4 quad q (0..3)
    int r = t >> 2, q = t & 3;
    int gm = m0 + r;
    long arow = (long)(gm >> 7) * SS + idx[gm];
    const float* Ap = seq + arow * (long)HH;
    const float* Bp = WT + (long)(n0 + r) * HH;

    // wave/lane geometry
    int w = t >> 6, lane = t & 63;
    int wr = w >> 1, wc = w & 1;         // wave tile: rows wr*32, cols wc*32
    int lrow = lane & 15, lk8 = (lane >> 4) * 8;

    f32x4 acc[2][2];
    #pragma unroll
    for (int mi = 0; mi < 2; ++mi)
        #pragma unroll
        for (int ni = 0; ni < 2; ++ni)
            #pragma unroll
            for (int j = 0; j < 4; ++j) acc[mi][ni][j] = 0.0f;

    for (int k0 = 0; k0 < HH; k0 += 32) {
        float4 a0 = *(const float4*)(Ap + k0 + q * 4);
        float4 a1 = *(const float4*)(Ap + k0 + 16 + q * 4);
        float4 b0 = *(const float4*)(Bp + k0 + q * 4);
        float4 b1 = *(const float4*)(Bp + k0 + 16 + q * 4);
        __syncthreads();  // previous compute done before overwrite
        ushort4 h, l;
        bsplit4(a0, h, l);
        *(ushort4*)&Ah[r * LSTR + q * 4] = h;  *(ushort4*)&Al[r * LSTR + q * 4] = l;
        bsplit4(a1, h, l);
        *(ushort4*)&Ah[r * LSTR + 16 + q * 4] = h;  *(ushort4*)&Al[r * LSTR + 16 + q * 4] = l;
        bsplit4(b0, h, l);
        *(ushort4*)&Bh[r * LSTR + q * 4] = h;  *(ushort4*)&Bl[r * LSTR + q * 4] = l;
        bsplit4(b1, h, l);
        *(ushort4*)&Bh[r * LSTR + 16 + q * 4] = h;  *(ushort4*)&Bl[r * LSTR + 16 + q * 4] = l;
        __syncthreads();

        bhalf8 ah0 = *(const bhalf8*)&Ah[(wr * 32 +  0 + lrow) * LSTR + lk8];
        bhalf8 ah1 = *(const bhalf8*)&Ah[(wr * 32 + 16 + lrow) * LSTR + lk8];
        bhalf8 al0 = *(const bhalf8*)&Al[(wr * 32 +  0 + lrow) * LSTR + lk8];
        bhalf8 al1 = *(const bhalf8*)&Al[(wr * 32 + 16 + lrow) * LSTR + lk8];
        #pragma unroll
        for (int ni = 0; ni < 2; ++ni) {
            bhalf8 bh = *(const bhalf8*)&Bh[(wc * 32 + ni * 16 + lrow) * LSTR + lk8];
            bhalf8 bl = *(const bhalf8*)&Bl[(wc * 32 + ni * 16 + lrow) * LSTR + lk8];
            acc[0][ni] = __builtin_amdgcn_mfma_f32_16x16x32_bf16(ah0, bh, acc[0][ni], 0, 0, 0);
            acc[0][ni] = __builtin_amdgcn_mfma_f32_16x16x32_bf16(al0, bh, acc[0][ni], 0, 0, 0);
            acc[0][ni] = __builtin_amdgcn_mfma_f32_16x16x32_bf16(ah0, bl, acc[0][ni], 0, 0, 0);
            acc[1][ni] = __builtin_amdgcn_mfma_f32_16x16x32_bf16(ah1, bh, acc[1][ni], 0, 0, 0);
            acc[1][ni] = __builtin_amdgcn_mfma_f32_16x16x32_bf16(al1, bh, acc[1][ni], 0, 0, 0);
            acc[1][ni] = __builtin_amdgcn_mfma_f32_16x16x32_bf16(ah1, bl, acc[1][ni], 0, 0, 0);
        }
    }

    // C/D layout (m89-verified): col = lane&15, row = (lane>>4)*4 + reg
    #pragma unroll
    for (int mi = 0; mi < 2; ++mi)
        #pragma unroll
        for (int ni = 0; ni < 2; ++ni)
            #pragma unroll
            for (int j = 0; j < 4; ++j) {
                int row = m0 + wr * 32 + mi * 16 + ((lane >> 4) << 2) + j;
                int col = n0 + wc * 32 + ni * 16 + lrow;
                C[(long)row * HH + col] = acc[mi][ni][j] + bias[col];
            }
}

// ---------------- Stage 3b: biaffine = tmp . val_reps^T + bbil ----------------
__global__ void biaffine_kernel(const float* __restrict__ TA,
                                const float* __restrict__ VB,
                                const float* __restrict__ bbil,
                                float* __restrict__ biaf) {
    __shared__ __align__(16) float As[16 * 68];
    __shared__ __align__(16) float Bs[16 * 68];
    int b = blockIdx.z;
    int m0 = blockIdx.y * 64, n0 = blockIdx.x * 64;
    int t = threadIdx.x;
    int tm = t >> 4, tn = t & 15;
    int lrow = t >> 2, lkq = t & 3;
    const float* Ap = TA + ((long)b * MAXC + m0 + lrow) * HH + lkq * 4;
    const float* Bp = VB + ((long)b * MAXC + n0 + lrow) * HH + lkq * 4;

    float acc[4][4];
    #pragma unroll
    for (int i = 0; i < 4; ++i)
        #pragma unroll
        for (int j = 0; j < 4; ++j) acc[i][j] = 0.0f;

    for (int k0 = 0; k0 < HH; k0 += 16) {
        float4 av = *(const float4*)(Ap + k0);
        float4 bv = *(const float4*)(Bp + k0);
        As[(lkq * 4 + 0) * 68 + lrow] = av.x;
        As[(lkq * 4 + 1) * 68 + lrow] = av.y;
        As[(lkq * 4 + 2) * 68 + lrow] = av.z;
        As[(lkq * 4 + 3) * 68 + lrow] = av.w;
        Bs[(lkq * 4 + 0) * 68 + lrow] = bv.x;
        Bs[(lkq * 4 + 1) * 68 + lrow] = bv.y;
        Bs[(lkq * 4 + 2) * 68 + lrow] = bv.z;
        Bs[(lkq * 4 + 3) * 68 + lrow] = bv.w;
        __syncthreads();
        #pragma unroll
        for (int kk = 0; kk < 16; ++kk) {
            float4 a4 = *(const float4*)&As[kk * 68 + tm * 4];
            float4 b4 = *(const float4*)&Bs[kk * 68 + tn * 4];
            float a[4] = {a4.x, a4.y, a4.z, a4.w};
            float bb2[4] = {b4.x, b4.y, b4.z, b4.w};
            #pragma unroll
            for (int i = 0; i < 4; ++i)
                #pragma unroll
                for (int j = 0; j < 4; ++j) acc[i][j] += a[i] * bb2[j];
        }
        __syncthreads();
    }

    float bb = bbil[0];
    #pragma unroll
    for (int i = 0; i < 4; ++i)
        #pragma unroll
        for (int j = 0; j < 4; ++j)
            biaf[((long)b * MAXC + m0 + tm * 4 + i) * MAXC + n0 + tn * 4 + j] =
                acc[i][j] + bb;
}

// ---------------- Stage 4: spatial features + fused MLPs + fusion head ----------------
__global__ void spatial_kernel(const float* __restrict__ bboxes,
                               const int* __restrict__ kidx,
                               const int* __restrict__ vidx,
                               const float* __restrict__ biaf,
                               const float* __restrict__ Ws1, const float* __restrict__ bs1,
                               const float* __restrict__ Ws2, const float* __restrict__ bs2,
                               const float* __restrict__ Wf1, const float* __restrict__ bf1,
                               const float* __restrict__ Wf2, const float* __restrict__ bf2,
                               float* __restrict__ out) {
    __shared__ float sW1[8 * 64], sb1[64], sW2[64 * 32], sb2[32];
    __shared__ float sF1[33 * 16], sf1b[16], sF2[16];
    __shared__ float sbf2;
    __shared__ float kb[16][4], vb[16][4];

    int b = blockIdx.z, kt = blockIdx.y, vt = blockIdx.x;
    int t = threadIdx.y * 16 + threadIdx.x;

    for (int i = t; i < 512; i += 256) sW1[i] = Ws1[i];
    for (int i = t; i < 2048; i += 256) sW2[i] = Ws2[i];
    for (int i = t; i < 528; i += 256) sF1[i] = Wf1[i];
    if (t < 64) sb1[t] = bs1[t];
    if (t >= 64 && t < 96) sb2[t - 64] = bs2[t - 64];
    if (t >= 96 && t < 112) sf1b[t - 96] = bf1[t - 96];
    if (t >= 112 && t < 128) sF2[t - 112] = Wf2[t - 112];
    if (t == 128) sbf2 = bf2[0];
    if (t < 64) {
        int r = t >> 2, c = t & 3;
        kb[r][c] = bboxes[((long)b * SS + kidx[b * MAXC + kt * 16 + r]) * 4 + c];
    } else if (t < 192 && t >= 128) {
        int q = t - 128; int r = q >> 2, c = q & 3;
        vb[r][c] = bboxes[((long)b * SS + vidx[b * MAXC + vt * 16 + r]) * 4 + c];
    }
    __syncthreads();

    int kr = threadIdx.y, vc = threadIdx.x;
    float k1 = kb[kr][0], k2 = kb[kr][1], k3 = kb[kr][2], k4 = kb[kr][3];
    float v1 = vb[vc][0], v2 = vb[vc][1], v3 = vb[vc][2], v4 = vb[vc][3];
    float kcx = (k1 + k3) * 0.5f, kcy = (k2 + k4) * 0.5f;
    float vcx = (v1 + v3) * 0.5f, vcy = (v2 + v4) * 0.5f;
    float dx = vcx - kcx, dy = vcy - kcy;
    float dist = sqrtf(dx * dx + dy * dy + FEPS);
    float angle = atan2f(dy, dx);
    float kh = k4 - k2, kw = k3 - k1, vh = v4 - v2, vw = v3 - v1;
    float h_ov = fmaxf(fminf(k4, v4) - fmaxf(k2, v2), 0.0f);
    float h_align = h_ov / (fminf(kh, vh) + FEPS);
    float v_ov = fmaxf(fminf(k3, v3) - fmaxf(k1, v1), 0.0f);
    float v_align = v_ov / (fminf(kw, vw) + FEPS);
    float area = (vh * vw) / (kh * kw + FEPS);
    float aspect = (vw / (vh + FEPS)) / (kw / (kh + FEPS));
    float sf[8] = {dx, dy, dist, angle, h_align, v_align, area, aspect};

    float h2[32];
    #pragma unroll
    for (int j = 0; j < 32; ++j) h2[j] = sb2[j];
    #pragma unroll 4
    for (int i = 0; i < 64; ++i) {
        float a = sb1[i];
        #pragma unroll
        for (int q = 0; q < 8; ++q) a += sf[q] * sW1[q * 64 + i];
        a = fmaxf(a, 0.0f);
        #pragma unroll
        for (int j = 0; j < 32; ++j) h2[j] += a * sW2[i * 32 + j];
    }

    int k = kt * 16 + kr, v = vt * 16 + vc;
    float bia = biaf[((long)b * MAXC + k) * MAXC + v];
    float sc = sbf2;
    #pragma unroll
    for (int j = 0; j < 16; ++j) {
        float f = sf1b[j] + bia * sF1[0 * 16 + j];
        #pragma unroll
        for (int i = 0; i < 32; ++i) f += h2[i] * sF1[(i + 1) * 16 + j];
        f = fmaxf(f, 0.0f);
        sc += f * sF2[j];
    }
    out[((long)b * MAXC + k) * MAXC + v] = sc;
}

extern "C" void kernel_launch(void* const* d_in, const int* in_sizes, int n_in,
                              void* d_out, int out_size, void* d_ws, size_t ws_size,
                              hipStream_t stream) {
    const float* seq    = (const float*)d_in[0];
    const float* logits = (const float*)d_in[1];
    const float* bboxes = (const float*)d_in[2];
    const int*   mask   = (const int*)d_in[3];
    const float* Wk  = (const float*)d_in[4];
    const float* bk  = (const float*)d_in[5];
    const float* Wv  = (const float*)d_in[6];
    const float* bv  = (const float*)d_in[7];
    const float* Wbil = (const float*)d_in[8];
    const float* bbil = (const float*)d_in[9];
    const float* Ws1 = (const float*)d_in[10];
    const float* bs1 = (const float*)d_in[11];
    const float* Ws2 = (const float*)d_in[12];
    const float* bs2 = (const float*)d_in[13];
    const float* Wf1 = (const float*)d_in[14];
    const float* bf1 = (const float*)d_in[15];
    const float* Wf2 = (const float*)d_in[16];
    const float* bf2 = (const float*)d_in[17];
    float* out = (float*)d_out;

    // workspace layout
    int* kidx = (int*)d_ws;
    int* vidx = kidx + BB * MAXC;
    float* U        = (float*)(vidx + BB * MAXC);            // [768,768]
    float* UT       = U + (size_t)HH * HH;                   // [768,768]
    float* WvT      = UT + (size_t)HH * HH;                  // [768,768]
    float* cvec     = WvT + (size_t)HH * HH;                 // [768]
    float* tmp      = cvec + HH;                             // [4096,768]
    float* val_reps = tmp + (size_t)BB * MAXC * HH;          // [4096,768]
    float* biaf     = val_reps + (size_t)BB * MAXC * HH;     // [32,128,128]

    topk_kernel<<<2 * BB, SS, 0, stream>>>(logits, mask, out, kidx, vidx);
    gemm_rowgather<<<dim3(12, 12), 256, 0, stream>>>(Wk, Wbil, nullptr, U, nullptr);
    bias_mm<<<3, 256, 0, stream>>>(bk, Wbil, cvec);
    transpose768<<<dim3(24, 24, 2), dim3(32, 8), 0, stream>>>(Wv, WvT, U, UT);
    gemm_dual_mfma<<<dim3(12, 64, 2), 256, 0, stream>>>(seq, UT, cvec, WvT, bv,
                                                        kidx, vidx, tmp, val_reps);
    biaffine_kernel<<<dim3(2, 2, BB), 256, 0, stream>>>(tmp, val_reps, bbil, biaf);
    spatial_kernel<<<dim3(8, 8, BB), dim3(16, 16), 0, stream>>>(
        bboxes, kidx, vidx, biaf, Ws1, bs1, Ws2, bs2, Wf1, bf1, Wf2, bf2, out);
}

// Round 11
// 323.284 us; speedup vs baseline: 1.8154x; 1.0734x over previous
//
#include <hip/hip_runtime.h>
#include <hip/hip_bf16.h>

#define BB 32
#define SS 512
#define HH 768
#define MAXC 128
#define FEPS 1e-8f

// d_out layout (floats, concatenated tuple in return order)
#define NSCORES (BB*MAXC*MAXC)            // 524288
#define OFF_KVALID (NSCORES)              // 524288
#define OFF_VVALID (OFF_KVALID + BB*MAXC) // 528384
#define OFF_KIDX   (OFF_VVALID + BB*MAXC) // 532480
#define OFF_VIDX   (OFF_KIDX + BB*MAXC)   // 536576

typedef __attribute__((ext_vector_type(8))) short bhalf8;  // 8 bf16 = 4 VGPR
typedef __attribute__((ext_vector_type(4))) float f32x4;   // MFMA acc

__device__ __forceinline__ unsigned int asc_map(float f) {
    unsigned int u = __float_as_uint(f);
    return (u & 0x80000000u) ? ~u : (u | 0x80000000u);
}

// bf16 split helpers (RNE, header-free)
__device__ __forceinline__ unsigned short f2bf_rne(float x) {
    unsigned u = __float_as_uint(x);
    unsigned r = u + 0x7FFFu + ((u >> 16) & 1u);
    return (unsigned short)(r >> 16);
}
__device__ __forceinline__ float bf2f(unsigned short h) {
    return __uint_as_float(((unsigned)h) << 16);
}
__device__ __forceinline__ void bsplit(float x, unsigned short& h, unsigned short& l) {
    h = f2bf_rne(x);
    l = f2bf_rne(x - bf2f(h));
}
__device__ __forceinline__ void bsplit4(float4 v, ushort4& h, ushort4& l) {
    bsplit(v.x, h.x, l.x); bsplit(v.y, h.y, l.y);
    bsplit(v.z, h.z, l.z); bsplit(v.w, h.w, l.w);
}

// ---------------- Stage 1: softmax/argmax/conf + stable top-128 ----------------
__global__ void topk_kernel(const float* __restrict__ logits,
                            const int* __restrict__ mask,
                            float* __restrict__ out,
                            int* __restrict__ kidx, int* __restrict__ vidx) {
    int z = blockIdx.x;
    int b = z >> 1;
    int which = z & 1;
    int t = threadIdx.x; // sequence position 0..511
    __shared__ unsigned long long keys[SS];

    const float* l = logits + ((size_t)b * SS + t) * 3;
    float l0 = l[0], l1 = l[1], l2 = l[2];
    int pred = 0; float best = l0;
    if (l1 > best) { best = l1; pred = 1; }
    if (l2 > best) { pred = 2; }
    float m = fmaxf(l0, fmaxf(l1, l2));
    float e0 = expf(l0 - m), e1 = expf(l1 - m), e2 = expf(l2 - m);
    float denom = e0 + e1 + e2;
    float p = (which == 0 ? e1 : e2) / denom;
    int want = which + 1;
    bool ok = (pred == want) && (mask[b * SS + t] == 1);
    float conf = ok ? p : -__builtin_inff();

    unsigned int d = ~asc_map(conf); // descending order map
    keys[t] = ((unsigned long long)d << 32) | (unsigned int)t;
    __syncthreads();

    for (int k = 2; k <= SS; k <<= 1) {
        for (int j = k >> 1; j > 0; j >>= 1) {
            int ixj = t ^ j;
            if (ixj > t) {
                unsigned long long a = keys[t], c = keys[ixj];
                bool up = ((t & k) == 0);
                bool sw = up ? (a > c) : (a < c);
                if (sw) { keys[t] = c; keys[ixj] = a; }
            }
            __syncthreads();
        }
    }

    if (t < MAXC) {
        unsigned long long kk = keys[t];
        int idx = (int)(kk & 0xFFFFFFFFu);
        bool valid = ((unsigned int)(kk >> 32)) != 0xFF800000u; // != map(-inf)
        if (which == 0) {
            kidx[b * MAXC + t] = idx;
            out[OFF_KVALID + b * MAXC + t] = valid ? 1.0f : 0.0f;
            out[OFF_KIDX + b * MAXC + t] = (float)idx;
        } else {
            vidx[b * MAXC + t] = idx;
            out[OFF_VVALID + b * MAXC + t] = valid ? 1.0f : 0.0f;
            out[OFF_VIDX + b * MAXC + t] = (float)idx;
        }
    }
}

// ---------------- fp32 GEMM body (proven R5 structure) — used for U = Wk@Wbil ----------------
__device__ __forceinline__ void gemm_body(float* __restrict__ As, float* __restrict__ Bs,
                                          const float* __restrict__ Arow,
                                          const float* __restrict__ Wp,
                                          const float* __restrict__ bias,
                                          float* __restrict__ C,
                                          int m0, int n0, int t) {
    const int N = HH, K = HH;
    int tm = t >> 4, tn = t & 15;
    int lrow = t >> 2, lkq = t & 3;
    int bkk = t >> 4, bnq = t & 15;

    float acc[4][4];
    #pragma unroll
    for (int i = 0; i < 4; ++i)
        #pragma unroll
        for (int j = 0; j < 4; ++j) acc[i][j] = 0.0f;

    for (int k0 = 0; k0 < K; k0 += 16) {
        float4 av = *(const float4*)(Arow + k0 + lkq * 4);
        As[(lkq * 4 + 0) * 68 + lrow] = av.x;
        As[(lkq * 4 + 1) * 68 + lrow] = av.y;
        As[(lkq * 4 + 2) * 68 + lrow] = av.z;
        As[(lkq * 4 + 3) * 68 + lrow] = av.w;
        float4 bv = *(const float4*)(Wp + (long)k0 * N);
        *(float4*)&Bs[bkk * 68 + bnq * 4] = bv;
        __syncthreads();
        #pragma unroll
        for (int kk = 0; kk < 16; ++kk) {
            float4 a4 = *(const float4*)&As[kk * 68 + tm * 4];
            float4 b4 = *(const float4*)&Bs[kk * 68 + tn * 4];
            float a[4] = {a4.x, a4.y, a4.z, a4.w};
            float bb2[4] = {b4.x, b4.y, b4.z, b4.w};
            #pragma unroll
            for (int i = 0; i < 4; ++i)
                #pragma unroll
                for (int j = 0; j < 4; ++j) acc[i][j] += a[i] * bb2[j];
        }
        __syncthreads();
    }

    #pragma unroll
    for (int i = 0; i < 4; ++i) {
        #pragma unroll
        for (int j = 0; j < 4; ++j) {
            int n = n0 + tn * 4 + j;
            float v = acc[i][j];
            if (bias) v += bias[n];
            C[(long)(m0 + tm * 4 + i) * N + n] = v;
        }
    }
}

__global__ void gemm_rowgather(const float* __restrict__ A,
                               const float* __restrict__ W,
                               const float* __restrict__ bias,
                               float* __restrict__ C,
                               const int* __restrict__ idx) {
    __shared__ __align__(16) float As[16 * 68];
    __shared__ __align__(16) float Bs[16 * 68];
    int t = threadIdx.x;
    int m0 = blockIdx.y * 64, n0 = blockIdx.x * 64;
    int gm = m0 + (t >> 2);
    long arow = idx ? ((long)(gm >> 7) * SS + idx[gm]) : gm;
    gemm_body(As, Bs, A + arow * (long)HH,
              W + (long)(t >> 4) * HH + n0 + (t & 15) * 4, bias, C, m0, n0, t);
}

// c[n] = sum_k bk[k] * Wbil[k][n]
__global__ void bias_mm(const float* __restrict__ bk, const float* __restrict__ Wbil,
                        float* __restrict__ c) {
    int n = blockIdx.x * 256 + threadIdx.x;
    if (n >= HH) return;
    float s0 = 0.0f, s1 = 0.0f, s2 = 0.0f, s3 = 0.0f;
    #pragma unroll 4
    for (int k = 0; k < HH; k += 4) {
        s0 += bk[k + 0] * Wbil[(long)(k + 0) * HH + n];
        s1 += bk[k + 1] * Wbil[(long)(k + 1) * HH + n];
        s2 += bk[k + 2] * Wbil[(long)(k + 2) * HH + n];
        s3 += bk[k + 3] * Wbil[(long)(k + 3) * HH + n];
    }
    c[n] = (s0 + s1) + (s2 + s3);
}

// ---------------- 768x768 transpose (z=0: Wv->WvT, z=1: U->UT) ----------------
__global__ void transpose768(const float* __restrict__ Wv, float* __restrict__ WvT,
                             const float* __restrict__ U, float* __restrict__ UT) {
    __shared__ float tile[32][33];
    const float* in  = blockIdx.z ? U  : Wv;
    float*       outp = blockIdx.z ? UT : WvT;
    int bx = blockIdx.x * 32, by = blockIdx.y * 32;
    int tx = threadIdx.x, ty = threadIdx.y; // (32,8)
    #pragma unroll
    for (int i = ty; i < 32; i += 8)
        tile[i][tx] = in[(long)(by + i) * HH + bx + tx];
    __syncthreads();
    #pragma unroll
    for (int i = ty; i < 32; i += 8)
        outp[(long)(bx + i) * HH + by + tx] = tile[tx][i];
}

// ---------------- split-bf16 MFMA dual GEMM ----------------
// z=0: tmp = gather_k(seq) @ U + cvec   (B operand staged from UT [n][k])
// z=1: val = gather_v(seq) @ Wv + bv    (B operand staged from WvT [n][k])
// 64x64 tile, BK=32, 4 waves (each 32x32 via 2x2 16x16 frags), single-buffer 2-barrier.
// A*B ~= Ah*Bh + Ah*Bl + Al*Bh  (bf16 hi/lo split, ~fp32 accuracy)
#define LSTR 40  // LDS row stride in shorts (80 B, 16B-aligned, conflict-light)

__global__ void gemm_dual_mfma(const float* __restrict__ seq,
                               const float* __restrict__ UT, const float* __restrict__ cvec,
                               const float* __restrict__ WvT, const float* __restrict__ bv,
                               const int* __restrict__ kidx, const int* __restrict__ vidx,
                               float* __restrict__ tmp, float* __restrict__ valr) {
    __shared__ unsigned short Ah[64 * LSTR], Al[64 * LSTR];
    __shared__ unsigned short Bh[64 * LSTR], Bl[64 * LSTR];
    int t = threadIdx.x;
    int m0 = blockIdx.y * 64, n0 = blockIdx.x * 64;
    int z = blockIdx.z;
    const int* idx = z ? vidx : kidx;
    const float* WT = z ? WvT : UT;
    const float* bias = z ? bv : cvec;
    float* C = z ? valr : tmp;

    // staging assignment: row r (0..63), float4 quad q (0..3)
    int r = t >> 2, q = t & 3;
    int gm = m0 + r;
    long arow = (long)(gm >> 7) * SS + idx[gm];
    const float* Ap = seq + arow * (long)HH;
    const float* Bp = WT + (long)(n0 + r) * HH;

    // wave/lane geometry
    int w = t >> 6, lane = t & 63;
    int wr = w >> 1, wc = w & 1;         // wave tile: rows wr*32, cols wc*32
    int lrow = lane & 15, lk8 = (lane >> 4) * 8;

    f32x4 acc[2][2];
    #pragma unroll
    for (int mi = 0; mi < 2; ++mi)
        #pragma unroll
        for (int ni = 0; ni < 2; ++ni)
            #pragma unroll
            for (int j = 0; j < 4; ++j) acc[mi][ni][j] = 0.0f;

    for (int k0 = 0; k0 < HH; k0 += 32) {
        float4 a0 = *(const float4*)(Ap + k0 + q * 4);
        float4 a1 = *(const float4*)(Ap + k0 + 16 + q * 4);
        float4 b0 = *(const float4*)(Bp + k0 + q * 4);
        float4 b1 = *(const float4*)(Bp + k0 + 16 + q * 4);
        __syncthreads();  // previous compute done before overwrite
        ushort4 h, l;
        bsplit4(a0, h, l);
        *(ushort4*)&Ah[r * LSTR + q * 4] = h;  *(ushort4*)&Al[r * LSTR + q * 4] = l;
        bsplit4(a1, h, l);
        *(ushort4*)&Ah[r * LSTR + 16 + q * 4] = h;  *(ushort4*)&Al[r * LSTR + 16 + q * 4] = l;
        bsplit4(b0, h, l);
        *(ushort4*)&Bh[r * LSTR + q * 4] = h;  *(ushort4*)&Bl[r * LSTR + q * 4] = l;
        bsplit4(b1, h, l);
        *(ushort4*)&Bh[r * LSTR + 16 + q * 4] = h;  *(ushort4*)&Bl[r * LSTR + 16 + q * 4] = l;
        __syncthreads();

        bhalf8 ah0 = *(const bhalf8*)&Ah[(wr * 32 +  0 + lrow) * LSTR + lk8];
        bhalf8 ah1 = *(const bhalf8*)&Ah[(wr * 32 + 16 + lrow) * LSTR + lk8];
        bhalf8 al0 = *(const bhalf8*)&Al[(wr * 32 +  0 + lrow) * LSTR + lk8];
        bhalf8 al1 = *(const bhalf8*)&Al[(wr * 32 + 16 + lrow) * LSTR + lk8];
        #pragma unroll
        for (int ni = 0; ni < 2; ++ni) {
            bhalf8 bh = *(const bhalf8*)&Bh[(wc * 32 + ni * 16 + lrow) * LSTR + lk8];
            bhalf8 bl = *(const bhalf8*)&Bl[(wc * 32 + ni * 16 + lrow) * LSTR + lk8];
            acc[0][ni] = __builtin_amdgcn_mfma_f32_16x16x32_bf16(ah0, bh, acc[0][ni], 0, 0, 0);
            acc[0][ni] = __builtin_amdgcn_mfma_f32_16x16x32_bf16(al0, bh, acc[0][ni], 0, 0, 0);
            acc[0][ni] = __builtin_amdgcn_mfma_f32_16x16x32_bf16(ah0, bl, acc[0][ni], 0, 0, 0);
            acc[1][ni] = __builtin_amdgcn_mfma_f32_16x16x32_bf16(ah1, bh, acc[1][ni], 0, 0, 0);
            acc[1][ni] = __builtin_amdgcn_mfma_f32_16x16x32_bf16(al1, bh, acc[1][ni], 0, 0, 0);
            acc[1][ni] = __builtin_amdgcn_mfma_f32_16x16x32_bf16(ah1, bl, acc[1][ni], 0, 0, 0);
        }
    }

    // C/D layout (m89-verified): col = lane&15, row = (lane>>4)*4 + reg
    #pragma unroll
    for (int mi = 0; mi < 2; ++mi)
        #pragma unroll
        for (int ni = 0; ni < 2; ++ni)
            #pragma unroll
            for (int j = 0; j < 4; ++j) {
                int row = m0 + wr * 32 + mi * 16 + ((lane >> 4) << 2) + j;
                int col = n0 + wc * 32 + ni * 16 + lrow;
                C[(long)row * HH + col] = acc[mi][ni][j] + bias[col];
            }
}

// ---------------- Stage 3b: biaffine = tmp . val_reps^T + bbil ----------------
__global__ void biaffine_kernel(const float* __restrict__ TA,
                                const float* __restrict__ VB,
                                const float* __restrict__ bbil,
                                float* __restrict__ biaf) {
    __shared__ __align__(16) float As[16 * 68];
    __shared__ __align__(16) float Bs[16 * 68];
    int b = blockIdx.z;
    int m0 = blockIdx.y * 64, n0 = blockIdx.x * 64;
    int t = threadIdx.x;
    int tm = t >> 4, tn = t & 15;
    int lrow = t >> 2, lkq = t & 3;
    const float* Ap = TA + ((long)b * MAXC + m0 + lrow) * HH + lkq * 4;
    const float* Bp = VB + ((long)b * MAXC + n0 + lrow) * HH + lkq * 4;

    float acc[4][4];
    #pragma unroll
    for (int i = 0; i < 4; ++i)
        #pragma unroll
        for (int j = 0; j < 4; ++j) acc[i][j] = 0.0f;

    for (int k0 = 0; k0 < HH; k0 += 16) {
        float4 av = *(const float4*)(Ap + k0);
        float4 bv = *(const float4*)(Bp + k0);
        As[(lkq * 4 + 0) * 68 + lrow] = av.x;
        As[(lkq * 4 + 1) * 68 + lrow] = av.y;
        As[(lkq * 4 + 2) * 68 + lrow] = av.z;
        As[(lkq * 4 + 3) * 68 + lrow] = av.w;
        Bs[(lkq * 4 + 0) * 68 + lrow] = bv.x;
        Bs[(lkq * 4 + 1) * 68 + lrow] = bv.y;
        Bs[(lkq * 4 + 2) * 68 + lrow] = bv.z;
        Bs[(lkq * 4 + 3) * 68 + lrow] = bv.w;
        __syncthreads();
        #pragma unroll
        for (int kk = 0; kk < 16; ++kk) {
            float4 a4 = *(const float4*)&As[kk * 68 + tm * 4];
            float4 b4 = *(const float4*)&Bs[kk * 68 + tn * 4];
            float a[4] = {a4.x, a4.y, a4.z, a4.w};
            float bb2[4] = {b4.x, b4.y, b4.z, b4.w};
            #pragma unroll
            for (int i = 0; i < 4; ++i)
                #pragma unroll
                for (int j = 0; j < 4; ++j) acc[i][j] += a[i] * bb2[j];
        }
        __syncthreads();
    }

    float bb = bbil[0];
    #pragma unroll
    for (int i = 0; i < 4; ++i)
        #pragma unroll
        for (int j = 0; j < 4; ++j)
            biaf[((long)b * MAXC + m0 + tm * 4 + i) * MAXC + n0 + tn * 4 + j] =
                acc[i][j] + bb;
}

// ---------------- Stage 4: spatial features + fused MLPs + fusion head ----------------
// Weights read DIRECTLY from global with wave-uniform indices -> compiler
// promotes to s_load (SGPR operands for v_fmac), freeing the DS pipe that
// bottlenecked the LDS-broadcast version (75us, VALUBusy 55%).
__global__ void spatial_kernel(const float* __restrict__ bboxes,
                               const int* __restrict__ kidx,
                               const int* __restrict__ vidx,
                               const float* __restrict__ biaf,
                               const float* __restrict__ Ws1, const float* __restrict__ bs1,
                               const float* __restrict__ Ws2, const float* __restrict__ bs2,
                               const float* __restrict__ Wf1, const float* __restrict__ bf1,
                               const float* __restrict__ Wf2, const float* __restrict__ bf2,
                               float* __restrict__ out) {
    __shared__ float kb[16][4], vb[16][4];

    int b = blockIdx.z, kt = blockIdx.y, vt = blockIdx.x;
    int t = threadIdx.y * 16 + threadIdx.x;

    if (t < 64) {
        int r = t >> 2, c = t & 3;
        kb[r][c] = bboxes[((long)b * SS + kidx[b * MAXC + kt * 16 + r]) * 4 + c];
    } else if (t < 192 && t >= 128) {
        int q = t - 128; int r = q >> 2, c = q & 3;
        vb[r][c] = bboxes[((long)b * SS + vidx[b * MAXC + vt * 16 + r]) * 4 + c];
    }
    __syncthreads();

    int kr = threadIdx.y, vc = threadIdx.x;
    float k1 = kb[kr][0], k2 = kb[kr][1], k3 = kb[kr][2], k4 = kb[kr][3];
    float v1 = vb[vc][0], v2 = vb[vc][1], v3 = vb[vc][2], v4 = vb[vc][3];
    float kcx = (k1 + k3) * 0.5f, kcy = (k2 + k4) * 0.5f;
    float vcx = (v1 + v3) * 0.5f, vcy = (v2 + v4) * 0.5f;
    float dx = vcx - kcx, dy = vcy - kcy;
    float dist = sqrtf(dx * dx + dy * dy + FEPS);
    float angle = atan2f(dy, dx);
    float kh = k4 - k2, kw = k3 - k1, vh = v4 - v2, vw = v3 - v1;
    float h_ov = fmaxf(fminf(k4, v4) - fmaxf(k2, v2), 0.0f);
    float h_align = h_ov / (fminf(kh, vh) + FEPS);
    float v_ov = fmaxf(fminf(k3, v3) - fmaxf(k1, v1), 0.0f);
    float v_align = v_ov / (fminf(kw, vw) + FEPS);
    float area = (vh * vw) / (kh * kw + FEPS);
    float aspect = (vw / (vh + FEPS)) / (kw / (kh + FEPS));
    float sf[8] = {dx, dy, dist, angle, h_align, v_align, area, aspect};

    // Fused MLP: layer1 row i -> immediately accumulated into h2[32].
    // All weight reads are loop-uniform -> scalar loads.
    float h2[32];
    #pragma unroll
    for (int j = 0; j < 32; ++j) h2[j] = bs2[j];
    #pragma unroll 4
    for (int i = 0; i < 64; ++i) {
        float a = bs1[i];
        #pragma unroll
        for (int q = 0; q < 8; ++q) a += sf[q] * Ws1[q * 64 + i];
        a = fmaxf(a, 0.0f);
        #pragma unroll
        for (int j = 0; j < 32; ++j) h2[j] += a * Ws2[i * 32 + j];
    }

    int k = kt * 16 + kr, v = vt * 16 + vc;
    float bia = biaf[((long)b * MAXC + k) * MAXC + v];
    float sc = bf2[0];
    #pragma unroll
    for (int j = 0; j < 16; ++j) {
        float f = bf1[j] + bia * Wf1[0 * 16 + j];
        #pragma unroll
        for (int i = 0; i < 32; ++i) f += h2[i] * Wf1[(i + 1) * 16 + j];
        f = fmaxf(f, 0.0f);
        sc += f * Wf2[j];
    }
    out[((long)b * MAXC + k) * MAXC + v] = sc;
}

extern "C" void kernel_launch(void* const* d_in, const int* in_sizes, int n_in,
                              void* d_out, int out_size, void* d_ws, size_t ws_size,
                              hipStream_t stream) {
    const float* seq    = (const float*)d_in[0];
    const float* logits = (const float*)d_in[1];
    const float* bboxes = (const float*)d_in[2];
    const int*   mask   = (const int*)d_in[3];
    const float* Wk  = (const float*)d_in[4];
    const float* bk  = (const float*)d_in[5];
    const float* Wv  = (const float*)d_in[6];
    const float* bv  = (const float*)d_in[7];
    const float* Wbil = (const float*)d_in[8];
    const float* bbil = (const float*)d_in[9];
    const float* Ws1 = (const float*)d_in[10];
    const float* bs1 = (const float*)d_in[11];
    const float* Ws2 = (const float*)d_in[12];
    const float* bs2 = (const float*)d_in[13];
    const float* Wf1 = (const float*)d_in[14];
    const float* bf1 = (const float*)d_in[15];
    const float* Wf2 = (const float*)d_in[16];
    const float* bf2 = (const float*)d_in[17];
    float* out = (float*)d_out;

    // workspace layout
    int* kidx = (int*)d_ws;
    int* vidx = kidx + BB * MAXC;
    float* U        = (float*)(vidx + BB * MAXC);            // [768,768]
    float* UT       = U + (size_t)HH * HH;                   // [768,768]
    float* WvT      = UT + (size_t)HH * HH;                  // [768,768]
    float* cvec     = WvT + (size_t)HH * HH;                 // [768]
    float* tmp      = cvec + HH;                             // [4096,768]
    float* val_reps = tmp + (size_t)BB * MAXC * HH;          // [4096,768]
    float* biaf     = val_reps + (size_t)BB * MAXC * HH;     // [32,128,128]

    topk_kernel<<<2 * BB, SS, 0, stream>>>(logits, mask, out, kidx, vidx);
    gemm_rowgather<<<dim3(12, 12), 256, 0, stream>>>(Wk, Wbil, nullptr, U, nullptr);
    bias_mm<<<3, 256, 0, stream>>>(bk, Wbil, cvec);
    transpose768<<<dim3(24, 24, 2), dim3(32, 8), 0, stream>>>(Wv, WvT, U, UT);
    gemm_dual_mfma<<<dim3(12, 64, 2), 256, 0, stream>>>(seq, UT, cvec, WvT, bv,
                                                        kidx, vidx, tmp, val_reps);
    biaffine_kernel<<<dim3(2, 2, BB), 256, 0, stream>>>(tmp, val_reps, bbil, biaf);
    spatial_kernel<<<dim3(8, 8, BB), dim3(16, 16), 0, stream>>>(
        bboxes, kidx, vidx, biaf, Ws1, bs1, Ws2, bs2, Wf1, bf1, Wf2, bf2, out);
}

// Round 12
// 298.734 us; speedup vs baseline: 1.9646x; 1.0822x over previous
//
#include <hip/hip_runtime.h>
#include <hip/hip_bf16.h>

#define BB 32
#define SS 512
#define HH 768
#define MAXC 128
#define FEPS 1e-8f

// d_out layout (floats, concatenated tuple in return order)
#define NSCORES (BB*MAXC*MAXC)            // 524288
#define OFF_KVALID (NSCORES)              // 524288
#define OFF_VVALID (OFF_KVALID + BB*MAXC) // 528384
#define OFF_KIDX   (OFF_VVALID + BB*MAXC) // 532480
#define OFF_VIDX   (OFF_KIDX + BB*MAXC)   // 536576

typedef __attribute__((ext_vector_type(8))) short bhalf8;          // MFMA A/B frag
typedef __attribute__((ext_vector_type(8))) unsigned short ush8;   // 16B bf16 vector
typedef __attribute__((ext_vector_type(4))) float f32x4;           // MFMA acc

__device__ __forceinline__ unsigned int asc_map(float f) {
    unsigned int u = __float_as_uint(f);
    return (u & 0x80000000u) ? ~u : (u | 0x80000000u);
}

// bf16 split helpers (RNE)
__device__ __forceinline__ unsigned short f2bf_rne(float x) {
    unsigned u = __float_as_uint(x);
    unsigned r = u + 0x7FFFu + ((u >> 16) & 1u);
    return (unsigned short)(r >> 16);
}
__device__ __forceinline__ float bf2f(unsigned short h) {
    return __uint_as_float(((unsigned)h) << 16);
}
__device__ __forceinline__ void bsplit(float x, unsigned short& h, unsigned short& l) {
    h = f2bf_rne(x);
    l = f2bf_rne(x - bf2f(h));
}
__device__ __forceinline__ void bsplit8(float4 a, float4 b, ush8& h, ush8& l) {
    unsigned short hh, ll;
    bsplit(a.x, hh, ll); h[0] = hh; l[0] = ll;
    bsplit(a.y, hh, ll); h[1] = hh; l[1] = ll;
    bsplit(a.z, hh, ll); h[2] = hh; l[2] = ll;
    bsplit(a.w, hh, ll); h[3] = hh; l[3] = ll;
    bsplit(b.x, hh, ll); h[4] = hh; l[4] = ll;
    bsplit(b.y, hh, ll); h[5] = hh; l[5] = ll;
    bsplit(b.z, hh, ll); h[6] = hh; l[6] = ll;
    bsplit(b.w, hh, ll); h[7] = hh; l[7] = ll;
}

// ---------------- Stage 1: softmax/argmax/conf + stable top-128 ----------------
__global__ void topk_kernel(const float* __restrict__ logits,
                            const int* __restrict__ mask,
                            float* __restrict__ out,
                            int* __restrict__ kidx, int* __restrict__ vidx) {
    int z = blockIdx.x;
    int b = z >> 1;
    int which = z & 1;
    int t = threadIdx.x; // sequence position 0..511
    __shared__ unsigned long long keys[SS];

    const float* l = logits + ((size_t)b * SS + t) * 3;
    float l0 = l[0], l1 = l[1], l2 = l[2];
    int pred = 0; float best = l0;
    if (l1 > best) { best = l1; pred = 1; }
    if (l2 > best) { pred = 2; }
    float m = fmaxf(l0, fmaxf(l1, l2));
    float e0 = expf(l0 - m), e1 = expf(l1 - m), e2 = expf(l2 - m);
    float denom = e0 + e1 + e2;
    float p = (which == 0 ? e1 : e2) / denom;
    int want = which + 1;
    bool ok = (pred == want) && (mask[b * SS + t] == 1);
    float conf = ok ? p : -__builtin_inff();

    unsigned int d = ~asc_map(conf); // descending order map
    keys[t] = ((unsigned long long)d << 32) | (unsigned int)t;
    __syncthreads();

    for (int k = 2; k <= SS; k <<= 1) {
        for (int j = k >> 1; j > 0; j >>= 1) {
            int ixj = t ^ j;
            if (ixj > t) {
                unsigned long long a = keys[t], c = keys[ixj];
                bool up = ((t & k) == 0);
                bool sw = up ? (a > c) : (a < c);
                if (sw) { keys[t] = c; keys[ixj] = a; }
            }
            __syncthreads();
        }
    }

    if (t < MAXC) {
        unsigned long long kk = keys[t];
        int idx = (int)(kk & 0xFFFFFFFFu);
        bool valid = ((unsigned int)(kk >> 32)) != 0xFF800000u; // != map(-inf)
        if (which == 0) {
            kidx[b * MAXC + t] = idx;
            out[OFF_KVALID + b * MAXC + t] = valid ? 1.0f : 0.0f;
            out[OFF_KIDX + b * MAXC + t] = (float)idx;
        } else {
            vidx[b * MAXC + t] = idx;
            out[OFF_VVALID + b * MAXC + t] = valid ? 1.0f : 0.0f;
            out[OFF_VIDX + b * MAXC + t] = (float)idx;
        }
    }
}

// c[n] = sum_k bk[k] * Wbil[k][n]
__global__ void bias_mm(const float* __restrict__ bk, const float* __restrict__ Wbil,
                        float* __restrict__ c) {
    int n = blockIdx.x * 256 + threadIdx.x;
    if (n >= HH) return;
    float s0 = 0.0f, s1 = 0.0f, s2 = 0.0f, s3 = 0.0f;
    #pragma unroll 4
    for (int k = 0; k < HH; k += 4) {
        s0 += bk[k + 0] * Wbil[(long)(k + 0) * HH + n];
        s1 += bk[k + 1] * Wbil[(long)(k + 1) * HH + n];
        s2 += bk[k + 2] * Wbil[(long)(k + 2) * HH + n];
        s3 += bk[k + 3] * Wbil[(long)(k + 3) * HH + n];
    }
    c[n] = (s0 + s1) + (s2 + s3);
}

// ---------------- transpose + bf16-split (z=0: Wv, z=1: Wbil) ----------------
__global__ void transpose_split(const float* __restrict__ Wv, const float* __restrict__ Wbil,
                                unsigned short* __restrict__ WvTh, unsigned short* __restrict__ WvTl,
                                unsigned short* __restrict__ WbilTh, unsigned short* __restrict__ WbilTl) {
    __shared__ float tile[32][33];
    const float* in = blockIdx.z ? Wbil : Wv;
    unsigned short* oh = blockIdx.z ? WbilTh : WvTh;
    unsigned short* ol = blockIdx.z ? WbilTl : WvTl;
    int bx = blockIdx.x * 32, by = blockIdx.y * 32;
    int tx = threadIdx.x, ty = threadIdx.y; // (32,8)
    #pragma unroll
    for (int i = ty; i < 32; i += 8)
        tile[i][tx] = in[(long)(by + i) * HH + bx + tx];
    __syncthreads();
    #pragma unroll
    for (int i = ty; i < 32; i += 8) {
        unsigned short h, l;
        bsplit(tile[tx][i], h, l);
        oh[(long)(bx + i) * HH + by + tx] = h;
        ol[(long)(bx + i) * HH + by + tx] = l;
    }
}

#define LSTR 40  // LDS row stride in shorts (80 B)

// ---------------- UT = Wbil^T @ Wk^T via split-bf16 MFMA ----------------
// UT[m][n] = sum_b WbilT[m][b] * Wk[n][b].  A = WbilT (pre-split), B = Wk rows
// (k-contiguous, in-loop split). Epilogue writes UT as bf16 hi/lo splits.
__global__ void ut_mfma(const unsigned short* __restrict__ WbilTh,
                        const unsigned short* __restrict__ WbilTl,
                        const float* __restrict__ Wk,
                        unsigned short* __restrict__ UTh, unsigned short* __restrict__ UTl) {
    __shared__ unsigned short Ah[64 * LSTR], Al[64 * LSTR];
    __shared__ unsigned short Bh[64 * LSTR], Bl[64 * LSTR];
    int t = threadIdx.x;
    int m0 = blockIdx.y * 64, n0 = blockIdx.x * 64;
    int r = t >> 2, q = t & 3;
    const unsigned short* Aph = WbilTh + (long)(m0 + r) * HH;
    const unsigned short* Apl = WbilTl + (long)(m0 + r) * HH;
    const float* Bp = Wk + (long)(n0 + r) * HH;

    int w = t >> 6, lane = t & 63;
    int wr = w >> 1, wc = w & 1;
    int lrow = lane & 15, lk8 = (lane >> 4) * 8;

    f32x4 acc[2][2];
    #pragma unroll
    for (int mi = 0; mi < 2; ++mi)
        #pragma unroll
        for (int ni = 0; ni < 2; ++ni)
            #pragma unroll
            for (int j = 0; j < 4; ++j) acc[mi][ni][j] = 0.0f;

    for (int k0 = 0; k0 < HH; k0 += 32) {
        ush8 ah = *(const ush8*)(Aph + k0 + q * 8);
        ush8 al = *(const ush8*)(Apl + k0 + q * 8);
        float4 b0 = *(const float4*)(Bp + k0 + q * 8);
        float4 b1 = *(const float4*)(Bp + k0 + q * 8 + 4);
        __syncthreads();
        *(ush8*)&Ah[r * LSTR + q * 8] = ah;
        *(ush8*)&Al[r * LSTR + q * 8] = al;
        ush8 bh, bl;
        bsplit8(b0, b1, bh, bl);
        *(ush8*)&Bh[r * LSTR + q * 8] = bh;
        *(ush8*)&Bl[r * LSTR + q * 8] = bl;
        __syncthreads();

        bhalf8 ah0 = *(const bhalf8*)&Ah[(wr * 32 +  0 + lrow) * LSTR + lk8];
        bhalf8 ah1 = *(const bhalf8*)&Ah[(wr * 32 + 16 + lrow) * LSTR + lk8];
        bhalf8 al0 = *(const bhalf8*)&Al[(wr * 32 +  0 + lrow) * LSTR + lk8];
        bhalf8 al1 = *(const bhalf8*)&Al[(wr * 32 + 16 + lrow) * LSTR + lk8];
        #pragma unroll
        for (int ni = 0; ni < 2; ++ni) {
            bhalf8 bh8 = *(const bhalf8*)&Bh[(wc * 32 + ni * 16 + lrow) * LSTR + lk8];
            bhalf8 bl8 = *(const bhalf8*)&Bl[(wc * 32 + ni * 16 + lrow) * LSTR + lk8];
            acc[0][ni] = __builtin_amdgcn_mfma_f32_16x16x32_bf16(ah0, bh8, acc[0][ni], 0, 0, 0);
            acc[0][ni] = __builtin_amdgcn_mfma_f32_16x16x32_bf16(al0, bh8, acc[0][ni], 0, 0, 0);
            acc[0][ni] = __builtin_amdgcn_mfma_f32_16x16x32_bf16(ah0, bl8, acc[0][ni], 0, 0, 0);
            acc[1][ni] = __builtin_amdgcn_mfma_f32_16x16x32_bf16(ah1, bh8, acc[1][ni], 0, 0, 0);
            acc[1][ni] = __builtin_amdgcn_mfma_f32_16x16x32_bf16(al1, bh8, acc[1][ni], 0, 0, 0);
            acc[1][ni] = __builtin_amdgcn_mfma_f32_16x16x32_bf16(ah1, bl8, acc[1][ni], 0, 0, 0);
        }
    }

    // write UT tile as bf16 splits (C/D layout: col=lane&15, row=(lane>>4)*4+j)
    #pragma unroll
    for (int mi = 0; mi < 2; ++mi)
        #pragma unroll
        for (int ni = 0; ni < 2; ++ni)
            #pragma unroll
            for (int j = 0; j < 4; ++j) {
                int row = m0 + wr * 32 + mi * 16 + ((lane >> 4) << 2) + j;
                int col = n0 + wc * 32 + ni * 16 + lrow;
                unsigned short h, l;
                bsplit(acc[mi][ni][j], h, l);
                UTh[(long)row * HH + col] = h;
                UTl[(long)row * HH + col] = l;
            }
}

// ---------------- split-bf16 MFMA dual GEMM (B pre-split) ----------------
// z=0: tmp = gather_k(seq) @ U + cvec   (B from UTh/UTl)
// z=1: val = gather_v(seq) @ Wv + bv    (B from WvTh/WvTl)
__global__ void gemm_dual_mfma(const float* __restrict__ seq,
                               const unsigned short* __restrict__ UTh,
                               const unsigned short* __restrict__ UTl,
                               const float* __restrict__ cvec,
                               const unsigned short* __restrict__ WvTh,
                               const unsigned short* __restrict__ WvTl,
                               const float* __restrict__ bv,
                               const int* __restrict__ kidx, const int* __restrict__ vidx,
                               float* __restrict__ tmp, float* __restrict__ valr) {
    __shared__ unsigned short Ah[64 * LSTR], Al[64 * LSTR];
    __shared__ unsigned short Bh[64 * LSTR], Bl[64 * LSTR];
    int t = threadIdx.x;
    int m0 = blockIdx.y * 64, n0 = blockIdx.x * 64;
    int z = blockIdx.z;
    const int* idx = z ? vidx : kidx;
    const unsigned short* BTh = z ? WvTh : UTh;
    const unsigned short* BTl = z ? WvTl : UTl;
    const float* bias = z ? bv : cvec;
    float* C = z ? valr : tmp;

    int r = t >> 2, q = t & 3;
    int gm = m0 + r;
    long arow = (long)(gm >> 7) * SS + idx[gm];
    const float* Ap = seq + arow * (long)HH;
    const unsigned short* Bph = BTh + (long)(n0 + r) * HH;
    const unsigned short* Bpl = BTl + (long)(n0 + r) * HH;

    int w = t >> 6, lane = t & 63;
    int wr = w >> 1, wc = w & 1;
    int lrow = lane & 15, lk8 = (lane >> 4) * 8;

    f32x4 acc[2][2];
    #pragma unroll
    for (int mi = 0; mi < 2; ++mi)
        #pragma unroll
        for (int ni = 0; ni < 2; ++ni)
            #pragma unroll
            for (int j = 0; j < 4; ++j) acc[mi][ni][j] = 0.0f;

    for (int k0 = 0; k0 < HH; k0 += 32) {
        float4 a0 = *(const float4*)(Ap + k0 + q * 8);
        float4 a1 = *(const float4*)(Ap + k0 + q * 8 + 4);
        ush8 bh = *(const ush8*)(Bph + k0 + q * 8);
        ush8 bl = *(const ush8*)(Bpl + k0 + q * 8);
        __syncthreads();  // previous compute done before overwrite
        ush8 ah, al;
        bsplit8(a0, a1, ah, al);
        *(ush8*)&Ah[r * LSTR + q * 8] = ah;
        *(ush8*)&Al[r * LSTR + q * 8] = al;
        *(ush8*)&Bh[r * LSTR + q * 8] = bh;
        *(ush8*)&Bl[r * LSTR + q * 8] = bl;
        __syncthreads();

        bhalf8 ah0 = *(const bhalf8*)&Ah[(wr * 32 +  0 + lrow) * LSTR + lk8];
        bhalf8 ah1 = *(const bhalf8*)&Ah[(wr * 32 + 16 + lrow) * LSTR + lk8];
        bhalf8 al0 = *(const bhalf8*)&Al[(wr * 32 +  0 + lrow) * LSTR + lk8];
        bhalf8 al1 = *(const bhalf8*)&Al[(wr * 32 + 16 + lrow) * LSTR + lk8];
        #pragma unroll
        for (int ni = 0; ni < 2; ++ni) {
            bhalf8 bh8 = *(const bhalf8*)&Bh[(wc * 32 + ni * 16 + lrow) * LSTR + lk8];
            bhalf8 bl8 = *(const bhalf8*)&Bl[(wc * 32 + ni * 16 + lrow) * LSTR + lk8];
            acc[0][ni] = __builtin_amdgcn_mfma_f32_16x16x32_bf16(ah0, bh8, acc[0][ni], 0, 0, 0);
            acc[0][ni] = __builtin_amdgcn_mfma_f32_16x16x32_bf16(al0, bh8, acc[0][ni], 0, 0, 0);
            acc[0][ni] = __builtin_amdgcn_mfma_f32_16x16x32_bf16(ah0, bl8, acc[0][ni], 0, 0, 0);
            acc[1][ni] = __builtin_amdgcn_mfma_f32_16x16x32_bf16(ah1, bh8, acc[1][ni], 0, 0, 0);
            acc[1][ni] = __builtin_amdgcn_mfma_f32_16x16x32_bf16(al1, bh8, acc[1][ni], 0, 0, 0);
            acc[1][ni] = __builtin_amdgcn_mfma_f32_16x16x32_bf16(ah1, bl8, acc[1][ni], 0, 0, 0);
        }
    }

    // C/D layout (m89-verified): col = lane&15, row = (lane>>4)*4 + reg
    #pragma unroll
    for (int mi = 0; mi < 2; ++mi)
        #pragma unroll
        for (int ni = 0; ni < 2; ++ni)
            #pragma unroll
            for (int j = 0; j < 4; ++j) {
                int row = m0 + wr * 32 + mi * 16 + ((lane >> 4) << 2) + j;
                int col = n0 + wc * 32 + ni * 16 + lrow;
                C[(long)row * HH + col] = acc[mi][ni][j] + bias[col];
            }
}

// ---------------- Stage 3b: biaffine = tmp . val_reps^T + bbil ----------------
__global__ void biaffine_kernel(const float* __restrict__ TA,
                                const float* __restrict__ VB,
                                const float* __restrict__ bbil,
                                float* __restrict__ biaf) {
    __shared__ __align__(16) float As[16 * 68];
    __shared__ __align__(16) float Bs[16 * 68];
    int b = blockIdx.z;
    int m0 = blockIdx.y * 64, n0 = blockIdx.x * 64;
    int t = threadIdx.x;
    int tm = t >> 4, tn = t & 15;
    int lrow = t >> 2, lkq = t & 3;
    const float* Ap = TA + ((long)b * MAXC + m0 + lrow) * HH + lkq * 4;
    const float* Bp = VB + ((long)b * MAXC + n0 + lrow) * HH + lkq * 4;

    float acc[4][4];
    #pragma unroll
    for (int i = 0; i < 4; ++i)
        #pragma unroll
        for (int j = 0; j < 4; ++j) acc[i][j] = 0.0f;

    for (int k0 = 0; k0 < HH; k0 += 16) {
        float4 av = *(const float4*)(Ap + k0);
        float4 bv = *(const float4*)(Bp + k0);
        As[(lkq * 4 + 0) * 68 + lrow] = av.x;
        As[(lkq * 4 + 1) * 68 + lrow] = av.y;
        As[(lkq * 4 + 2) * 68 + lrow] = av.z;
        As[(lkq * 4 + 3) * 68 + lrow] = av.w;
        Bs[(lkq * 4 + 0) * 68 + lrow] = bv.x;
        Bs[(lkq * 4 + 1) * 68 + lrow] = bv.y;
        Bs[(lkq * 4 + 2) * 68 + lrow] = bv.z;
        Bs[(lkq * 4 + 3) * 68 + lrow] = bv.w;
        __syncthreads();
        #pragma unroll
        for (int kk = 0; kk < 16; ++kk) {
            float4 a4 = *(const float4*)&As[kk * 68 + tm * 4];
            float4 b4 = *(const float4*)&Bs[kk * 68 + tn * 4];
            float a[4] = {a4.x, a4.y, a4.z, a4.w};
            float bb2[4] = {b4.x, b4.y, b4.z, b4.w};
            #pragma unroll
            for (int i = 0; i < 4; ++i)
                #pragma unroll
                for (int j = 0; j < 4; ++j) acc[i][j] += a[i] * bb2[j];
        }
        __syncthreads();
    }

    float bb = bbil[0];
    #pragma unroll
    for (int i = 0; i < 4; ++i)
        #pragma unroll
        for (int j = 0; j < 4; ++j)
            biaf[((long)b * MAXC + m0 + tm * 4 + i) * MAXC + n0 + tn * 4 + j] =
                acc[i][j] + bb;
}

// ---------------- Stage 4: spatial features + fused MLPs + fusion head ----------------
// Weights read directly from global with wave-uniform indices -> scalar loads.
__global__ void spatial_kernel(const float* __restrict__ bboxes,
                               const int* __restrict__ kidx,
                               const int* __restrict__ vidx,
                               const float* __restrict__ biaf,
                               const float* __restrict__ Ws1, const float* __restrict__ bs1,
                               const float* __restrict__ Ws2, const float* __restrict__ bs2,
                               const float* __restrict__ Wf1, const float* __restrict__ bf1,
                               const float* __restrict__ Wf2, const float* __restrict__ bf2,
                               float* __restrict__ out) {
    __shared__ float kb[16][4], vb[16][4];

    int b = blockIdx.z, kt = blockIdx.y, vt = blockIdx.x;
    int t = threadIdx.y * 16 + threadIdx.x;

    if (t < 64) {
        int r = t >> 2, c = t & 3;
        kb[r][c] = bboxes[((long)b * SS + kidx[b * MAXC + kt * 16 + r]) * 4 + c];
    } else if (t < 192 && t >= 128) {
        int q = t - 128; int r = q >> 2, c = q & 3;
        vb[r][c] = bboxes[((long)b * SS + vidx[b * MAXC + vt * 16 + r]) * 4 + c];
    }
    __syncthreads();

    int kr = threadIdx.y, vc = threadIdx.x;
    float k1 = kb[kr][0], k2 = kb[kr][1], k3 = kb[kr][2], k4 = kb[kr][3];
    float v1 = vb[vc][0], v2 = vb[vc][1], v3 = vb[vc][2], v4 = vb[vc][3];
    float kcx = (k1 + k3) * 0.5f, kcy = (k2 + k4) * 0.5f;
    float vcx = (v1 + v3) * 0.5f, vcy = (v2 + v4) * 0.5f;
    float dx = vcx - kcx, dy = vcy - kcy;
    float dist = sqrtf(dx * dx + dy * dy + FEPS);
    float angle = atan2f(dy, dx);
    float kh = k4 - k2, kw = k3 - k1, vh = v4 - v2, vw = v3 - v1;
    float h_ov = fmaxf(fminf(k4, v4) - fmaxf(k2, v2), 0.0f);
    float h_align = h_ov / (fminf(kh, vh) + FEPS);
    float v_ov = fmaxf(fminf(k3, v3) - fmaxf(k1, v1), 0.0f);
    float v_align = v_ov / (fminf(kw, vw) + FEPS);
    float area = (vh * vw) / (kh * kw + FEPS);
    float aspect = (vw / (vh + FEPS)) / (kw / (kh + FEPS));
    float sf[8] = {dx, dy, dist, angle, h_align, v_align, area, aspect};

    float h2[32];
    #pragma unroll
    for (int j = 0; j < 32; ++j) h2[j] = bs2[j];
    #pragma unroll 4
    for (int i = 0; i < 64; ++i) {
        float a = bs1[i];
        #pragma unroll
        for (int q = 0; q < 8; ++q) a += sf[q] * Ws1[q * 64 + i];
        a = fmaxf(a, 0.0f);
        #pragma unroll
        for (int j = 0; j < 32; ++j) h2[j] += a * Ws2[i * 32 + j];
    }

    int k = kt * 16 + kr, v = vt * 16 + vc;
    float bia = biaf[((long)b * MAXC + k) * MAXC + v];
    float sc = bf2[0];
    #pragma unroll
    for (int j = 0; j < 16; ++j) {
        float f = bf1[j] + bia * Wf1[0 * 16 + j];
        #pragma unroll
        for (int i = 0; i < 32; ++i) f += h2[i] * Wf1[(i + 1) * 16 + j];
        f = fmaxf(f, 0.0f);
        sc += f * Wf2[j];
    }
    out[((long)b * MAXC + k) * MAXC + v] = sc;
}

extern "C" void kernel_launch(void* const* d_in, const int* in_sizes, int n_in,
                              void* d_out, int out_size, void* d_ws, size_t ws_size,
                              hipStream_t stream) {
    const float* seq    = (const float*)d_in[0];
    const float* logits = (const float*)d_in[1];
    const float* bboxes = (const float*)d_in[2];
    const int*   mask   = (const int*)d_in[3];
    const float* Wk  = (const float*)d_in[4];
    const float* bk  = (const float*)d_in[5];
    const float* Wv  = (const float*)d_in[6];
    const float* bv  = (const float*)d_in[7];
    const float* Wbil = (const float*)d_in[8];
    const float* bbil = (const float*)d_in[9];
    const float* Ws1 = (const float*)d_in[10];
    const float* bs1 = (const float*)d_in[11];
    const float* Ws2 = (const float*)d_in[12];
    const float* bs2 = (const float*)d_in[13];
    const float* Wf1 = (const float*)d_in[14];
    const float* bf1 = (const float*)d_in[15];
    const float* Wf2 = (const float*)d_in[16];
    const float* bf2 = (const float*)d_in[17];
    float* out = (float*)d_out;

    // workspace layout (~34.4 MB, matches prior proven footprint)
    int* kidx = (int*)d_ws;
    int* vidx = kidx + BB * MAXC;
    unsigned short* WvTh   = (unsigned short*)(vidx + BB * MAXC);
    unsigned short* WvTl   = WvTh   + (size_t)HH * HH;
    unsigned short* WbilTh = WvTl   + (size_t)HH * HH;
    unsigned short* WbilTl = WbilTh + (size_t)HH * HH;
    unsigned short* UTh    = WbilTl + (size_t)HH * HH;
    unsigned short* UTl    = UTh    + (size_t)HH * HH;
    float* cvec     = (float*)(UTl + (size_t)HH * HH);
    float* tmp      = cvec + HH;                             // [4096,768]
    float* val_reps = tmp + (size_t)BB * MAXC * HH;          // [4096,768]
    float* biaf     = val_reps + (size_t)BB * MAXC * HH;     // [32,128,128]

    topk_kernel<<<2 * BB, SS, 0, stream>>>(logits, mask, out, kidx, vidx);
    transpose_split<<<dim3(24, 24, 2), dim3(32, 8), 0, stream>>>(
        Wv, Wbil, WvTh, WvTl, WbilTh, WbilTl);
    bias_mm<<<3, 256, 0, stream>>>(bk, Wbil, cvec);
    ut_mfma<<<dim3(12, 12), 256, 0, stream>>>(WbilTh, WbilTl, Wk, UTh, UTl);
    gemm_dual_mfma<<<dim3(12, 64, 2), 256, 0, stream>>>(
        seq, UTh, UTl, cvec, WvTh, WvTl, bv, kidx, vidx, tmp, val_reps);
    biaffine_kernel<<<dim3(2, 2, BB), 256, 0, stream>>>(tmp, val_reps, bbil, biaf);
    spatial_kernel<<<dim3(8, 8, BB), dim3(16, 16), 0, stream>>>(
        bboxes, kidx, vidx, biaf, Ws1, bs1, Ws2, bs2, Wf1, bf1, Wf2, bf2, out);
}